// Round 1
// baseline (1979.723 us; speedup 1.0000x reference)
//
#include <hip/hip_runtime.h>
#include <hip/hip_bf16.h>
#include <cstdint>

#define TOPK 50
#define HIST_BINS 16384
#define CAND_CAP 8192

// ---------------------------------------------------------------------------
// K0: prep — build combined weight Wc[256][512] = [W1_top | W1_bot], zero hist,
// detect int64-vs-int32 edge_index layout, zero counters.
// ---------------------------------------------------------------------------
__global__ void prep_kernel(const float* __restrict__ W1, float* __restrict__ Wc,
                            unsigned* __restrict__ hist, unsigned* __restrict__ misc,
                            const int* __restrict__ eidx) {
    int i = blockIdx.x * blockDim.x + threadIdx.x;
    if (i < 256 * 512) {
        int k = i >> 9;        // 0..255
        int j = i & 511;       // 0..511
        Wc[i] = (j < 256) ? W1[k * 256 + j] : W1[(k + 256) * 256 + (j - 256)];
    }
    if (i < HIST_BINS) hist[i] = 0;
    if (i == 0) {
        // int64 detection: little-endian high words of first 64 entries all zero
        int allz = 1;
        for (int q = 0; q < 64; ++q)
            if (eidx[2 * q + 1] != 0) { allz = 0; break; }
        misc[0] = (unsigned)allz;  // 1 => int64 layout
        misc[2] = 0;               // threshold bits
        misc[3] = 0;               // candidate counter
    }
}

// ---------------------------------------------------------------------------
// K1: node GEMM  AB[M][512] = emb[M][256] @ Wc[256][512]  (+ b1 on cols<256)
// 128x128 tile, 256 threads, 8x8 micro-tile, BK=16.
// ---------------------------------------------------------------------------
#define BM 128
#define BN 128
#define BK 16
#define LDS_STRIDE 132

__global__ __launch_bounds__(256) void gemm_node(const float* __restrict__ emb,
                                                 const float* __restrict__ Wc,
                                                 const float* __restrict__ b1,
                                                 float* __restrict__ AB, int M) {
    __shared__ float As[BK][LDS_STRIDE];
    __shared__ float Bs[BK][LDS_STRIDE];
    const int m0 = blockIdx.x * BM;
    const int n0 = blockIdx.y * BN;
    const int t = threadIdx.x;
    const int tx = t & 15;   // 0..15 -> col group
    const int ty = t >> 4;   // 0..15 -> row group

    float acc[8][8];
#pragma unroll
    for (int i = 0; i < 8; ++i)
#pragma unroll
        for (int j = 0; j < 8; ++j) acc[i][j] = 0.f;

    for (int kt = 0; kt < 256; kt += BK) {
        // A tile: 128 rows x 16 k -> transposed As[k][m]
#pragma unroll
        for (int it = 0; it < 2; ++it) {
            int r = (t >> 2) + it * 64;       // 0..127
            int kk = (t & 3) * 4;             // 0,4,8,12
            int gr = m0 + r;
            float4 v = make_float4(0.f, 0.f, 0.f, 0.f);
            if (gr < M) v = *(const float4*)&emb[(size_t)gr * 256 + kt + kk];
            As[kk + 0][r] = v.x;
            As[kk + 1][r] = v.y;
            As[kk + 2][r] = v.z;
            As[kk + 3][r] = v.w;
        }
        // B tile: 16 k x 128 n
#pragma unroll
        for (int it = 0; it < 2; ++it) {
            int flat = t * 8 + it * 4;        // 0..2044
            int kk = flat >> 7;               // 0..15
            int nn = flat & 127;
            float4 v = *(const float4*)&Wc[(size_t)(kt + kk) * 512 + n0 + nn];
            *(float4*)&Bs[kk][nn] = v;
        }
        __syncthreads();
#pragma unroll
        for (int k = 0; k < BK; ++k) {
            float a[8], b[8];
            *(float4*)&a[0] = *(const float4*)&As[k][ty * 8];
            *(float4*)&a[4] = *(const float4*)&As[k][ty * 8 + 4];
            *(float4*)&b[0] = *(const float4*)&Bs[k][tx * 8];
            *(float4*)&b[4] = *(const float4*)&Bs[k][tx * 8 + 4];
#pragma unroll
            for (int i = 0; i < 8; ++i)
#pragma unroll
                for (int j = 0; j < 8; ++j) acc[i][j] += a[i] * b[j];
        }
        __syncthreads();
    }

    // epilogue
#pragma unroll
    for (int i = 0; i < 8; ++i) {
        int gr = m0 + ty * 8 + i;
        if (gr < M) {
#pragma unroll
            for (int j = 0; j < 8; j += 4) {
                int gc = n0 + tx * 8 + j;
                float4 v = *(float4*)&acc[i][j];
                if (gc < 256) {
                    v.x += b1[gc];
                    v.y += b1[gc + 1];
                    v.z += b1[gc + 2];
                    v.w += b1[gc + 3];
                }
                *(float4*)&AB[(size_t)gr * 512 + gc] = v;
            }
        }
    }
}

// ---------------------------------------------------------------------------
// K2: edge scoring — one wave per edge. score = sigmoid(relu(A[src]+B[dst])·W2 + b2)
// Also builds the 16-bit-prefix histogram for valid scores.
// ---------------------------------------------------------------------------
__global__ __launch_bounds__(256) void edge_score(const float* __restrict__ AB,
                                                  const int* __restrict__ eidx,
                                                  const float* __restrict__ W2,
                                                  const float* __restrict__ b2,
                                                  float* __restrict__ scores,
                                                  unsigned* __restrict__ hist,
                                                  const unsigned* __restrict__ misc,
                                                  int E) {
    const int lane = threadIdx.x & 63;
    const int wid = (blockIdx.x * (blockDim.x >> 6)) + (threadIdx.x >> 6);
    const int nwaves = gridDim.x * (blockDim.x >> 6);
    const int is64 = (int)misc[0];
    const float4 w2 = *(const float4*)&W2[lane * 4];
    const float bb2 = b2[0];

    for (int e = wid; e < E; e += nwaves) {
        int src, dst;
        if (is64) {
            src = eidx[2 * (size_t)e];
            dst = eidx[2 * ((size_t)e + E)];
        } else {
            src = eidx[e];
            dst = eidx[e + E];
        }
        if (src >= dst) {
            if (lane == 0) scores[e] = -1.0f;
            continue;
        }
        const float4 a = *(const float4*)&AB[(size_t)src * 512 + lane * 4];
        const float4 b = *(const float4*)&AB[(size_t)dst * 512 + 256 + lane * 4];
        float p = fmaxf(a.x + b.x, 0.f) * w2.x;
        p += fmaxf(a.y + b.y, 0.f) * w2.y;
        p += fmaxf(a.z + b.z, 0.f) * w2.z;
        p += fmaxf(a.w + b.w, 0.f) * w2.w;
#pragma unroll
        for (int off = 32; off; off >>= 1) p += __shfl_xor(p, off, 64);
        if (lane == 0) {
            float z = p + bb2;
            float sc = 1.0f / (1.0f + expf(-z));
            scores[e] = sc;
            atomicAdd(&hist[__float_as_uint(sc) >> 16], 1u);
        }
    }
}

// ---------------------------------------------------------------------------
// K3: scan histogram from top, find threshold bin containing rank TOPK
// ---------------------------------------------------------------------------
__global__ void scan_hist(const unsigned* __restrict__ hist, unsigned* __restrict__ misc) {
    __shared__ unsigned chunk[256];
    int t = threadIdx.x;
    unsigned s = 0;
    for (int i = 0; i < 64; ++i) s += hist[t * 64 + i];
    chunk[t] = s;
    __syncthreads();
    if (t == 0) {
        unsigned cum = 0;
        int c;
        unsigned thr = 0;
        for (c = 255; c >= 0; --c) {
            if (cum + chunk[c] >= TOPK) break;
            cum += chunk[c];
        }
        if (c >= 0) {
            for (int b = c * 64 + 63; b >= c * 64; --b) {
                cum += hist[b];
                if (cum >= TOPK) { thr = ((unsigned)b) << 16; break; }
            }
        }
        misc[2] = thr;
    }
}

// ---------------------------------------------------------------------------
// K4: compact candidates with score bits >= threshold
// ---------------------------------------------------------------------------
__global__ void compact(const float* __restrict__ scores, unsigned* __restrict__ misc,
                        unsigned long long* __restrict__ cand, int E) {
    const unsigned thr = misc[2];
    int i = blockIdx.x * blockDim.x + threadIdx.x;
    int stride = gridDim.x * blockDim.x;
    for (int e = i; e < E; e += stride) {
        float s = scores[e];
        if (s < 0.f) continue;
        unsigned bits = __float_as_uint(s);
        if (bits >= thr) {
            unsigned pos = atomicAdd(&misc[3], 1u);
            if (pos < CAND_CAP)
                cand[pos] = ((unsigned long long)bits << 32) | (unsigned)(0xFFFFFFFFu - (unsigned)e);
        }
    }
}

// ---------------------------------------------------------------------------
// K5: final top-K selection (single block). Tie-break: lower edge index first
// (encoded: key = bits<<32 | (~e), max key == higher score, then lower e).
// ---------------------------------------------------------------------------
__global__ void final_topk(unsigned long long* __restrict__ cand,
                           const unsigned* __restrict__ misc,
                           const int* __restrict__ eidx,
                           float* __restrict__ out, int E) {
    __shared__ unsigned long long red[256];
    const int t = threadIdx.x;
    const int C = (int)min(misc[3], (unsigned)CAND_CAP);
    const int is64 = (int)misc[0];
    for (int r = 0; r < TOPK; ++r) {
        unsigned long long best = 0ull;
        for (int i = t; i < C; i += 256) {
            unsigned long long v = cand[i];
            if (v > best) best = v;
        }
        red[t] = best;
        __syncthreads();
        for (int s = 128; s; s >>= 1) {
            if (t < s) {
                if (red[t + s] > red[t]) red[t] = red[t + s];
            }
            __syncthreads();
        }
        unsigned long long m = red[0];
        __syncthreads();
        // remove winner
        for (int i = t; i < C; i += 256)
            if (cand[i] == m) cand[i] = 0ull;
        if (t == 0) {
            if (m != 0ull) {
                unsigned bits = (unsigned)(m >> 32);
                unsigned e = 0xFFFFFFFFu - (unsigned)(m & 0xFFFFFFFFu);
                int src, dst;
                if (is64) {
                    src = eidx[2 * (size_t)e];
                    dst = eidx[2 * ((size_t)e + E)];
                } else {
                    src = eidx[e];
                    dst = eidx[e + E];
                }
                out[r] = (float)src;
                out[TOPK + r] = (float)dst;
                out[2 * TOPK + r] = __uint_as_float(bits);
            } else {
                out[r] = -1.f;
                out[TOPK + r] = -1.f;
                out[2 * TOPK + r] = -1.f;
            }
        }
        __syncthreads();
    }
}

// ---------------------------------------------------------------------------
extern "C" void kernel_launch(void* const* d_in, const int* in_sizes, int n_in,
                              void* d_out, int out_size, void* d_ws, size_t ws_size,
                              hipStream_t stream) {
    const float* emb = (const float*)d_in[0];
    const float* W1  = (const float*)d_in[1];
    const float* b1  = (const float*)d_in[2];
    const float* W2  = (const float*)d_in[3];
    const float* b2  = (const float*)d_in[4];
    const int*   eidx = (const int*)d_in[5];

    const int M = in_sizes[0] / 256;   // 50000 nodes
    const int E = in_sizes[5] / 2;     // 800000 edges

    char* ws = (char*)d_ws;
    float* Wc = (float*)ws;                                   // 1 MB
    float* AB = (float*)(ws + (1 << 20));                     // M*512*4 bytes
    size_t abBytes = (size_t)M * 512 * 4;
    float* scores = (float*)(ws + (1 << 20) + abBytes);       // E*4 bytes
    unsigned* hist = (unsigned*)((char*)scores + (size_t)E * 4);
    unsigned long long* cand = (unsigned long long*)((char*)hist + HIST_BINS * 4);
    unsigned* misc = (unsigned*)((char*)cand + CAND_CAP * 8);

    float* out = (float*)d_out;

    // K0: prep
    prep_kernel<<<512, 256, 0, stream>>>(W1, Wc, hist, misc, eidx);

    // K1: node GEMM
    dim3 ggrid((M + BM - 1) / BM, 512 / BN);
    gemm_node<<<ggrid, 256, 0, stream>>>(emb, Wc, b1, AB, M);

    // K2: edge scoring + histogram
    edge_score<<<2048, 256, 0, stream>>>(AB, eidx, W2, b2, scores, hist, misc, E);

    // K3: threshold scan
    scan_hist<<<1, 256, 0, stream>>>(hist, misc);

    // K4: compaction
    compact<<<1024, 256, 0, stream>>>(scores, misc, cand, E);

    // K5: final selection + output
    final_topk<<<1, 256, 0, stream>>>(cand, misc, eidx, out, E);
}

// Round 3
// 1467.254 us; speedup vs baseline: 1.3493x; 1.3493x over previous
//
#include <hip/hip_runtime.h>
#include <hip/hip_bf16.h>
#include <cstdint>

#define TOPK 50
#define HIST_BINS 16384
#define CAND_CAP 8192

// ---------------------------------------------------------------------------
// K0: prep — build combined weight Wc[256][512] = [W1_top | W1_bot], zero hist,
// detect int64-vs-int32 edge_index layout, zero counters.
// ---------------------------------------------------------------------------
__global__ void prep_kernel(const float* __restrict__ W1, float* __restrict__ Wc,
                            unsigned* __restrict__ hist, unsigned* __restrict__ misc,
                            const int* __restrict__ eidx) {
    int i = blockIdx.x * blockDim.x + threadIdx.x;
    if (i < 256 * 512) {
        int k = i >> 9;        // 0..255
        int j = i & 511;       // 0..511
        Wc[i] = (j < 256) ? W1[k * 256 + j] : W1[(k + 256) * 256 + (j - 256)];
    }
    if (i < HIST_BINS) hist[i] = 0;
    if (i == 0) {
        // int64 detection: little-endian high words of first 64 entries all zero
        int allz = 1;
        for (int q = 0; q < 64; ++q)
            if (eidx[2 * q + 1] != 0) { allz = 0; break; }
        misc[0] = (unsigned)allz;  // 1 => int64 layout
        misc[2] = 0;               // threshold bits
        misc[3] = 0;               // candidate counter
        misc[4] = 0;               // valid-edge counter
    }
}

// ---------------------------------------------------------------------------
// K1: node GEMM  AB[M][512] = emb[M][256] @ Wc[256][512]  (+ b1 on cols<256)
// ---------------------------------------------------------------------------
#define BM 128
#define BN 128
#define BK 16
#define LDS_STRIDE 132

__global__ __launch_bounds__(256) void gemm_node(const float* __restrict__ emb,
                                                 const float* __restrict__ Wc,
                                                 const float* __restrict__ b1,
                                                 float* __restrict__ AB, int M) {
    __shared__ float As[BK][LDS_STRIDE];
    __shared__ float Bs[BK][LDS_STRIDE];
    const int m0 = blockIdx.x * BM;
    const int n0 = blockIdx.y * BN;
    const int t = threadIdx.x;
    const int tx = t & 15;
    const int ty = t >> 4;

    float acc[8][8];
#pragma unroll
    for (int i = 0; i < 8; ++i)
#pragma unroll
        for (int j = 0; j < 8; ++j) acc[i][j] = 0.f;

    for (int kt = 0; kt < 256; kt += BK) {
#pragma unroll
        for (int it = 0; it < 2; ++it) {
            int r = (t >> 2) + it * 64;
            int kk = (t & 3) * 4;
            int gr = m0 + r;
            float4 v = make_float4(0.f, 0.f, 0.f, 0.f);
            if (gr < M) v = *(const float4*)&emb[(size_t)gr * 256 + kt + kk];
            As[kk + 0][r] = v.x;
            As[kk + 1][r] = v.y;
            As[kk + 2][r] = v.z;
            As[kk + 3][r] = v.w;
        }
#pragma unroll
        for (int it = 0; it < 2; ++it) {
            int flat = t * 8 + it * 4;
            int kk = flat >> 7;
            int nn = flat & 127;
            float4 v = *(const float4*)&Wc[(size_t)(kt + kk) * 512 + n0 + nn];
            *(float4*)&Bs[kk][nn] = v;
        }
        __syncthreads();
#pragma unroll
        for (int k = 0; k < BK; ++k) {
            float a[8], b[8];
            *(float4*)&a[0] = *(const float4*)&As[k][ty * 8];
            *(float4*)&a[4] = *(const float4*)&As[k][ty * 8 + 4];
            *(float4*)&b[0] = *(const float4*)&Bs[k][tx * 8];
            *(float4*)&b[4] = *(const float4*)&Bs[k][tx * 8 + 4];
#pragma unroll
            for (int i = 0; i < 8; ++i)
#pragma unroll
                for (int j = 0; j < 8; ++j) acc[i][j] += a[i] * b[j];
        }
        __syncthreads();
    }

#pragma unroll
    for (int i = 0; i < 8; ++i) {
        int gr = m0 + ty * 8 + i;
        if (gr < M) {
#pragma unroll
            for (int j = 0; j < 8; j += 4) {
                int gc = n0 + tx * 8 + j;
                float4 v = *(float4*)&acc[i][j];
                if (gc < 256) {
                    v.x += b1[gc];
                    v.y += b1[gc + 1];
                    v.z += b1[gc + 2];
                    v.w += b1[gc + 3];
                }
                *(float4*)&AB[(size_t)gr * 512 + gc] = v;
            }
        }
    }
}

// ---------------------------------------------------------------------------
// K2a: filter — compact valid edges (src<dst) into dense vsrc/vdst/vid arrays.
// Per-wave ballot aggregation: one atomic per wave.
// ---------------------------------------------------------------------------
__global__ __launch_bounds__(256) void filter_edges(const int* __restrict__ eidx,
                                                    unsigned* __restrict__ misc,
                                                    int* __restrict__ vsrc,
                                                    int* __restrict__ vdst,
                                                    int* __restrict__ vid, int E) {
    const int is64 = (int)misc[0];
    const int lane = threadIdx.x & 63;
    int i = blockIdx.x * blockDim.x + threadIdx.x;
    int stride = gridDim.x * blockDim.x;
    for (int e = i; e < E; e += stride) {
        int s, d;
        if (is64) {
            int2 t0 = ((const int2*)eidx)[e];
            int2 t1 = ((const int2*)eidx)[(size_t)e + E];
            s = t0.x; d = t1.x;
        } else {
            s = eidx[e];
            d = eidx[e + E];
        }
        bool valid = s < d;
        unsigned long long mask = __ballot(valid);
        unsigned cnt = __popcll(mask);
        unsigned pfx = __popcll(mask & ((1ull << lane) - 1ull));
        unsigned basep = 0;
        if (lane == 0 && cnt) basep = atomicAdd(&misc[4], cnt);
        basep = __shfl(basep, 0, 64);
        if (valid) {
            int p = (int)(basep + pfx);
            vsrc[p] = s;
            vdst[p] = d;
            vid[p] = e;
        }
    }
}

// ---------------------------------------------------------------------------
// K2b: edge scoring over dense valid list. 16 lanes per edge, 4 edges/wave.
// score = sigmoid(relu(A[src]+B[dst])·W2 + b2); histogram of top-16 score bits.
// ---------------------------------------------------------------------------
__global__ __launch_bounds__(256) void edge_score2(const float* __restrict__ AB,
                                                   const int* __restrict__ vsrc,
                                                   const int* __restrict__ vdst,
                                                   const float* __restrict__ W2,
                                                   const float* __restrict__ b2,
                                                   float* __restrict__ svals,
                                                   unsigned* __restrict__ hist,
                                                   const unsigned* __restrict__ misc) {
    const int V = (int)misc[4];
    const int lane = threadIdx.x & 63;
    const int q = lane & 15;   // element group within edge
    const int g = lane >> 4;   // edge slot within wave (0..3)
    const int wid = blockIdx.x * (blockDim.x >> 6) + (threadIdx.x >> 6);
    const int nw = gridDim.x * (blockDim.x >> 6);

    // W2 slice for this lane: elements q*16 .. q*16+15
    const float4 w0 = *(const float4*)&W2[q * 16 + 0];
    const float4 w1 = *(const float4*)&W2[q * 16 + 4];
    const float4 w2 = *(const float4*)&W2[q * 16 + 8];
    const float4 w3 = *(const float4*)&W2[q * 16 + 12];
    const float bb2 = b2[0];

    for (int base = wid * 4; base < V; base += nw * 4) {
        const int slot = base + g;
        const bool ok = slot < V;
        const int src = ok ? vsrc[slot] : 0;
        const int dst = ok ? vdst[slot] : 0;
        const float4* pa = (const float4*)&AB[(size_t)src * 512 + q * 16];
        const float4* pb = (const float4*)&AB[(size_t)dst * 512 + 256 + q * 16];
        // 8 independent loads in flight
        const float4 a0 = pa[0], a1 = pa[1], a2 = pa[2], a3 = pa[3];
        const float4 c0 = pb[0], c1 = pb[1], c2 = pb[2], c3 = pb[3];
        float p;
        p  = fmaxf(a0.x + c0.x, 0.f) * w0.x;
        p += fmaxf(a0.y + c0.y, 0.f) * w0.y;
        p += fmaxf(a0.z + c0.z, 0.f) * w0.z;
        p += fmaxf(a0.w + c0.w, 0.f) * w0.w;
        p += fmaxf(a1.x + c1.x, 0.f) * w1.x;
        p += fmaxf(a1.y + c1.y, 0.f) * w1.y;
        p += fmaxf(a1.z + c1.z, 0.f) * w1.z;
        p += fmaxf(a1.w + c1.w, 0.f) * w1.w;
        p += fmaxf(a2.x + c2.x, 0.f) * w2.x;
        p += fmaxf(a2.y + c2.y, 0.f) * w2.y;
        p += fmaxf(a2.z + c2.z, 0.f) * w2.z;
        p += fmaxf(a2.w + c2.w, 0.f) * w2.w;
        p += fmaxf(a3.x + c3.x, 0.f) * w3.x;
        p += fmaxf(a3.y + c3.y, 0.f) * w3.y;
        p += fmaxf(a3.z + c3.z, 0.f) * w3.z;
        p += fmaxf(a3.w + c3.w, 0.f) * w3.w;
        // reduce within 16-lane group
        p += __shfl_xor(p, 1, 64);
        p += __shfl_xor(p, 2, 64);
        p += __shfl_xor(p, 4, 64);
        p += __shfl_xor(p, 8, 64);
        if (q == 0 && ok) {
            float z = p + bb2;
            float sc = 1.0f / (1.0f + expf(-z));
            svals[slot] = sc;
            atomicAdd(&hist[__float_as_uint(sc) >> 16], 1u);
        }
    }
}

// ---------------------------------------------------------------------------
// K3: scan histogram from top, find threshold bin containing rank TOPK
// ---------------------------------------------------------------------------
__global__ void scan_hist(const unsigned* __restrict__ hist, unsigned* __restrict__ misc) {
    __shared__ unsigned chunk[256];
    int t = threadIdx.x;
    unsigned s = 0;
    for (int i = 0; i < 64; ++i) s += hist[t * 64 + i];
    chunk[t] = s;
    __syncthreads();
    if (t == 0) {
        unsigned cum = 0;
        int c;
        unsigned thr = 0;
        for (c = 255; c >= 0; --c) {
            if (cum + chunk[c] >= TOPK) break;
            cum += chunk[c];
        }
        if (c >= 0) {
            for (int b = c * 64 + 63; b >= c * 64; --b) {
                cum += hist[b];
                if (cum >= TOPK) { thr = ((unsigned)b) << 16; break; }
            }
        }
        misc[2] = thr;
    }
}

// ---------------------------------------------------------------------------
// K4: compact candidates (score bits >= threshold) from dense score array
// ---------------------------------------------------------------------------
__global__ void compact(const float* __restrict__ svals, const int* __restrict__ vid,
                        unsigned* __restrict__ misc,
                        unsigned long long* __restrict__ cand) {
    const int V = (int)misc[4];
    const unsigned thr = misc[2];
    int i = blockIdx.x * blockDim.x + threadIdx.x;
    int stride = gridDim.x * blockDim.x;
    for (int v = i; v < V; v += stride) {
        unsigned bits = __float_as_uint(svals[v]);
        if (bits >= thr) {
            unsigned pos = atomicAdd(&misc[3], 1u);
            if (pos < CAND_CAP)
                cand[pos] = ((unsigned long long)bits << 32) |
                            (unsigned)(0xFFFFFFFFu - (unsigned)vid[v]);
        }
    }
}

// ---------------------------------------------------------------------------
// K5: final top-K selection (single block). key = bits<<32 | ~e
// (max key == higher score, then lower edge index — jax tie-break).
// ---------------------------------------------------------------------------
__global__ void final_topk(unsigned long long* __restrict__ cand,
                           const unsigned* __restrict__ misc,
                           const int* __restrict__ eidx,
                           float* __restrict__ out, int E) {
    __shared__ unsigned long long red[256];
    const int t = threadIdx.x;
    const int C = (int)min(misc[3], (unsigned)CAND_CAP);
    const int is64 = (int)misc[0];
    for (int r = 0; r < TOPK; ++r) {
        unsigned long long best = 0ull;
        for (int i = t; i < C; i += 256) {
            unsigned long long v = cand[i];
            if (v > best) best = v;
        }
        red[t] = best;
        __syncthreads();
        for (int s = 128; s; s >>= 1) {
            if (t < s) {
                if (red[t + s] > red[t]) red[t] = red[t + s];
            }
            __syncthreads();
        }
        unsigned long long m = red[0];
        __syncthreads();
        for (int i = t; i < C; i += 256)
            if (cand[i] == m) cand[i] = 0ull;
        if (t == 0) {
            if (m != 0ull) {
                unsigned bits = (unsigned)(m >> 32);
                unsigned e = 0xFFFFFFFFu - (unsigned)(m & 0xFFFFFFFFu);
                int src, dst;
                if (is64) {
                    src = eidx[2 * (size_t)e];
                    dst = eidx[2 * ((size_t)e + E)];
                } else {
                    src = eidx[e];
                    dst = eidx[e + E];
                }
                out[r] = (float)src;
                out[TOPK + r] = (float)dst;
                out[2 * TOPK + r] = __uint_as_float(bits);
            } else {
                out[r] = -1.f;
                out[TOPK + r] = -1.f;
                out[2 * TOPK + r] = -1.f;
            }
        }
        __syncthreads();
    }
}

// ---------------------------------------------------------------------------
extern "C" void kernel_launch(void* const* d_in, const int* in_sizes, int n_in,
                              void* d_out, int out_size, void* d_ws, size_t ws_size,
                              hipStream_t stream) {
    const float* emb = (const float*)d_in[0];
    const float* W1  = (const float*)d_in[1];
    const float* b1  = (const float*)d_in[2];
    const float* W2  = (const float*)d_in[3];
    const float* b2  = (const float*)d_in[4];
    const int*   eidx = (const int*)d_in[5];

    const int M = in_sizes[0] / 256;   // 50000 nodes
    const int E = in_sizes[5] / 2;     // 800000 edges

    char* ws = (char*)d_ws;
    float* Wc = (float*)ws;                                   // 1 MB
    float* AB = (float*)(ws + (1 << 20));                     // M*512*4
    size_t abBytes = (size_t)M * 512 * 4;
    char* p = ws + (1 << 20) + abBytes;
    float* svals = (float*)p;              p += (size_t)E * 4;
    int* vsrc = (int*)p;                   p += (size_t)E * 4;
    int* vdst = (int*)p;                   p += (size_t)E * 4;
    int* vid  = (int*)p;                   p += (size_t)E * 4;
    unsigned* hist = (unsigned*)p;         p += HIST_BINS * 4;
    unsigned long long* cand = (unsigned long long*)p; p += CAND_CAP * 8;
    unsigned* misc = (unsigned*)p;

    float* out = (float*)d_out;

    prep_kernel<<<512, 256, 0, stream>>>(W1, Wc, hist, misc, eidx);

    dim3 ggrid((M + BM - 1) / BM, 512 / BN);
    gemm_node<<<ggrid, 256, 0, stream>>>(emb, Wc, b1, AB, M);

    filter_edges<<<1024, 256, 0, stream>>>(eidx, misc, vsrc, vdst, vid, E);

    edge_score2<<<2048, 256, 0, stream>>>(AB, vsrc, vdst, W2, b2, svals, hist, misc);

    scan_hist<<<1, 256, 0, stream>>>(hist, misc);

    compact<<<1024, 256, 0, stream>>>(svals, vid, misc, cand);

    final_topk<<<1, 256, 0, stream>>>(cand, misc, eidx, out, E);
}

// Round 4
// 1348.560 us; speedup vs baseline: 1.4680x; 1.0880x over previous
//
#include <hip/hip_runtime.h>
#include <hip/hip_bf16.h>
#include <cstdint>

#define TOPK 50
#define CANDS 400          // rank margin for approx threshold
#define HIST_BINS 16384
#define CAND_CAP 16384

typedef __attribute__((ext_vector_type(8))) short bf16x8;
typedef __attribute__((ext_vector_type(4))) float f32x4;

__device__ __forceinline__ unsigned short f2bf(float f) {
    unsigned u = __float_as_uint(f);
    u += 0x7FFFu + ((u >> 16) & 1u);   // RNE
    return (unsigned short)(u >> 16);
}

// ---------------------------------------------------------------------------
// K0: prep — build Wc B-fragments (bf16, MFMA 16x16x32 layout), zero hist,
// detect int64 layout, zero counters.
// Wcfrag chunk (nt,kt): 64 lanes x 16B; lane l holds Wc[k=kt*32+(l>>4)*8+j][col=nt*16+(l&15)]
// where Wc[k][c] = c<256 ? W1[k][c] : W1[256+k][c-256].
// ---------------------------------------------------------------------------
__global__ __launch_bounds__(256) void prep_kernel(const float* __restrict__ W1,
                                                   unsigned* __restrict__ Wcf4,
                                                   unsigned* __restrict__ hist,
                                                   unsigned* __restrict__ misc,
                                                   const int* __restrict__ eidx) {
    int g = blockIdx.x * blockDim.x + threadIdx.x;   // 0..16383
    {
        int l = g & 63;
        int kt = (g >> 6) & 7;
        int nt = g >> 9;                 // 0..31
        int col = nt * 16 + (l & 15);
        int kb = kt * 32 + (l >> 4) * 8;
        unsigned short h[8];
#pragma unroll
        for (int j = 0; j < 8; ++j) {
            int k = kb + j;
            float f = (col < 256) ? W1[k * 256 + col] : W1[(256 + k) * 256 + (col - 256)];
            h[j] = f2bf(f);
        }
        unsigned* dst = Wcf4 + (size_t)g * 4;
        dst[0] = (unsigned)h[0] | ((unsigned)h[1] << 16);
        dst[1] = (unsigned)h[2] | ((unsigned)h[3] << 16);
        dst[2] = (unsigned)h[4] | ((unsigned)h[5] << 16);
        dst[3] = (unsigned)h[6] | ((unsigned)h[7] << 16);
    }
    if (g < HIST_BINS) hist[g] = 0;
    if (g == 0) {
        int allz = 1;
        for (int q = 0; q < 64; ++q)
            if (eidx[2 * q + 1] != 0) { allz = 0; break; }
        misc[0] = (unsigned)allz;  // 1 => int64 layout
        misc[2] = 0;               // threshold bits
        misc[3] = 0;               // candidate counter
        misc[4] = 0;               // valid-edge counter
    }
}

// ---------------------------------------------------------------------------
// K1: emb fp32 -> A-fragments bf16 (MFMA layout). One block per m-tile (16 rows).
// A8f chunk (mt,kt): lane l holds emb[mt*16 + (l&15)][kt*32 + (l>>4)*8 + j], j=0..7
// ---------------------------------------------------------------------------
__global__ __launch_bounds__(256) void cvt_emb(const float* __restrict__ emb,
                                               unsigned* __restrict__ A8f4, int M) {
    __shared__ float sl[16][260];
    const int mt = blockIdx.x;
    const int t = threadIdx.x;
    {
        int row = t >> 4;
        int c0 = (t & 15) * 16;
        int gr = mt * 16 + row;
        float4 v0, v1, v2, v3;
        if (gr < M) {
            const float* sp = emb + (size_t)gr * 256 + c0;
            v0 = *(const float4*)(sp + 0);
            v1 = *(const float4*)(sp + 4);
            v2 = *(const float4*)(sp + 8);
            v3 = *(const float4*)(sp + 12);
        } else {
            v0 = v1 = v2 = v3 = make_float4(0.f, 0.f, 0.f, 0.f);
        }
        *(float4*)&sl[row][c0 + 0] = v0;
        *(float4*)&sl[row][c0 + 4] = v1;
        *(float4*)&sl[row][c0 + 8] = v2;
        *(float4*)&sl[row][c0 + 12] = v3;
    }
    __syncthreads();
    const int w = t >> 6;
    const int l = t & 63;
    const int r = l & 15;
    const int kb0 = (l >> 4) * 8;
#pragma unroll
    for (int it = 0; it < 2; ++it) {
        int kt = w + it * 4;
        int kb = kt * 32 + kb0;
        unsigned short h[8];
#pragma unroll
        for (int j = 0; j < 8; ++j) h[j] = f2bf(sl[r][kb + j]);
        unsigned* dst = A8f4 + ((size_t)(mt * 8 + kt) * 64 + l) * 4;
        dst[0] = (unsigned)h[0] | ((unsigned)h[1] << 16);
        dst[1] = (unsigned)h[2] | ((unsigned)h[3] << 16);
        dst[2] = (unsigned)h[4] | ((unsigned)h[5] << 16);
        dst[3] = (unsigned)h[6] | ((unsigned)h[7] << 16);
    }
}

// ---------------------------------------------------------------------------
// K2: no-LDS fragment GEMM. C[Mpad][512] = emb @ Wc, epilogue adds b1 (cols<256)
// and stores fp8 e4m3 bytes. Block 128x128 (4 waves, 2x2), K-loop 8 x 32.
// ---------------------------------------------------------------------------
__global__ __launch_bounds__(256) void gemm_frag(const bf16x8* __restrict__ A8v,
                                                 const bf16x8* __restrict__ Bv,
                                                 const float* __restrict__ b1,
                                                 unsigned char* __restrict__ C8) {
    const int bm = blockIdx.x;
    const int bn = blockIdx.y;
    const int t = threadIdx.x;
    const int w = t >> 6;
    const int l = t & 63;
    const int wm = w >> 1, wn = w & 1;

    f32x4 acc[4][4];
#pragma unroll
    for (int i = 0; i < 4; ++i)
#pragma unroll
        for (int j = 0; j < 4; ++j) acc[i][j] = (f32x4){0.f, 0.f, 0.f, 0.f};

    const int MT0 = bm * 8 + wm * 4;
    const int NT0 = bn * 8 + wn * 4;
#pragma unroll
    for (int kt = 0; kt < 8; ++kt) {
        bf16x8 af[4], bf_[4];
#pragma unroll
        for (int i = 0; i < 4; ++i) af[i] = A8v[(size_t)((MT0 + i) * 8 + kt) * 64 + l];
#pragma unroll
        for (int j = 0; j < 4; ++j) bf_[j] = Bv[(size_t)((NT0 + j) * 8 + kt) * 64 + l];
#pragma unroll
        for (int i = 0; i < 4; ++i)
#pragma unroll
            for (int j = 0; j < 4; ++j)
                acc[i][j] = __builtin_amdgcn_mfma_f32_16x16x32_bf16(af[i], bf_[j], acc[i][j], 0, 0, 0);
    }

    const int row0 = bm * 128 + wm * 64 + (l >> 4) * 4;
    const int col0 = bn * 128 + wn * 64 + (l & 15);
#pragma unroll
    for (int i = 0; i < 4; ++i) {
#pragma unroll
        for (int j = 0; j < 4; ++j) {
            int col = col0 + j * 16;
            float bias = (col < 256) ? b1[col] : 0.f;
#pragma unroll
            for (int r = 0; r < 4; ++r) {
                int row = row0 + i * 16 + r;
                float v = acc[i][j][r] + bias;
                int pk = __builtin_amdgcn_cvt_pk_fp8_f32(v, v, 0, false);
                C8[(size_t)row * 512 + col] = (unsigned char)(pk & 0xFF);
            }
        }
    }
}

// ---------------------------------------------------------------------------
// K3: filter — compact valid edges (src<dst) into dense vsrc/vdst/vid.
// ---------------------------------------------------------------------------
__global__ __launch_bounds__(256) void filter_edges(const int* __restrict__ eidx,
                                                    unsigned* __restrict__ misc,
                                                    int* __restrict__ vsrc,
                                                    int* __restrict__ vdst,
                                                    int* __restrict__ vid, int E) {
    const int is64 = (int)misc[0];
    const int lane = threadIdx.x & 63;
    int i = blockIdx.x * blockDim.x + threadIdx.x;
    int stride = gridDim.x * blockDim.x;
    for (int e = i; e < E; e += stride) {
        int s, d;
        if (is64) {
            int2 t0 = ((const int2*)eidx)[e];
            int2 t1 = ((const int2*)eidx)[(size_t)e + E];
            s = t0.x; d = t1.x;
        } else {
            s = eidx[e];
            d = eidx[e + E];
        }
        bool valid = s < d;
        unsigned long long mask = __ballot(valid);
        unsigned cnt = __popcll(mask);
        unsigned pfx = __popcll(mask & ((1ull << lane) - 1ull));
        unsigned basep = 0;
        if (lane == 0 && cnt) basep = atomicAdd(&misc[4], cnt);
        basep = __shfl(basep, 0, 64);
        if (valid) {
            int p = (int)(basep + pfx);
            vsrc[p] = s;
            vdst[p] = d;
            vid[p] = e;
        }
    }
}

// ---------------------------------------------------------------------------
// K4: fp8 edge scoring. 16 lanes/edge, 4 edges/wave. One dwordx4 per side/lane.
// ---------------------------------------------------------------------------
__device__ __forceinline__ float dotq(unsigned a, unsigned b, float4 w) {
    float s;
    s  = fmaxf(__builtin_amdgcn_cvt_f32_fp8(a, 0) + __builtin_amdgcn_cvt_f32_fp8(b, 0), 0.f) * w.x;
    s += fmaxf(__builtin_amdgcn_cvt_f32_fp8(a, 1) + __builtin_amdgcn_cvt_f32_fp8(b, 1), 0.f) * w.y;
    s += fmaxf(__builtin_amdgcn_cvt_f32_fp8(a, 2) + __builtin_amdgcn_cvt_f32_fp8(b, 2), 0.f) * w.z;
    s += fmaxf(__builtin_amdgcn_cvt_f32_fp8(a, 3) + __builtin_amdgcn_cvt_f32_fp8(b, 3), 0.f) * w.w;
    return s;
}

__global__ __launch_bounds__(256) void edge_score_fp8(const unsigned char* __restrict__ C8,
                                                      const int* __restrict__ vsrc,
                                                      const int* __restrict__ vdst,
                                                      const float* __restrict__ W2,
                                                      const float* __restrict__ b2,
                                                      float* __restrict__ svals,
                                                      unsigned* __restrict__ hist,
                                                      const unsigned* __restrict__ misc) {
    const int V = (int)misc[4];
    const int lane = threadIdx.x & 63;
    const int q = lane & 15;
    const int g = lane >> 4;
    const int wid = blockIdx.x * (blockDim.x >> 6) + (threadIdx.x >> 6);
    const int nw = gridDim.x * (blockDim.x >> 6);

    const float4 w0 = *(const float4*)&W2[q * 16 + 0];
    const float4 w1 = *(const float4*)&W2[q * 16 + 4];
    const float4 w2 = *(const float4*)&W2[q * 16 + 8];
    const float4 w3 = *(const float4*)&W2[q * 16 + 12];
    const float bb2 = b2[0];

    for (int base = wid * 4; base < V; base += nw * 4) {
        const int slot = base + g;
        const bool ok = slot < V;
        const int src = ok ? vsrc[slot] : 0;
        const int dst = ok ? vdst[slot] : 0;
        const uint4 ua = *(const uint4*)(C8 + (size_t)src * 512 + q * 16);
        const uint4 ub = *(const uint4*)(C8 + (size_t)dst * 512 + 256 + q * 16);
        float p = dotq(ua.x, ub.x, w0);
        p += dotq(ua.y, ub.y, w1);
        p += dotq(ua.z, ub.z, w2);
        p += dotq(ua.w, ub.w, w3);
        p += __shfl_xor(p, 1, 64);
        p += __shfl_xor(p, 2, 64);
        p += __shfl_xor(p, 4, 64);
        p += __shfl_xor(p, 8, 64);
        if (q == 0 && ok) {
            float z = p + bb2;
            float sc = 1.0f / (1.0f + expf(-z));
            svals[slot] = sc;
            atomicAdd(&hist[__float_as_uint(sc) >> 16], 1u);
        }
    }
}

// ---------------------------------------------------------------------------
// K5: scan histogram from top — threshold bin containing approx rank CANDS
// ---------------------------------------------------------------------------
__global__ void scan_hist(const unsigned* __restrict__ hist, unsigned* __restrict__ misc) {
    __shared__ unsigned chunk[256];
    int t = threadIdx.x;
    unsigned s = 0;
    for (int i = 0; i < 64; ++i) s += hist[t * 64 + i];
    chunk[t] = s;
    __syncthreads();
    if (t == 0) {
        unsigned cum = 0;
        int c;
        unsigned thr = 0;
        for (c = 255; c >= 0; --c) {
            if (cum + chunk[c] >= CANDS) break;
            cum += chunk[c];
        }
        if (c >= 0) {
            for (int b = c * 64 + 63; b >= c * 64; --b) {
                cum += hist[b];
                if (cum >= CANDS) { thr = ((unsigned)b) << 16; break; }
            }
        }
        misc[2] = thr;
    }
}

// ---------------------------------------------------------------------------
// K6: compact candidates (approx score bits >= threshold)
// ---------------------------------------------------------------------------
__global__ void compact(const float* __restrict__ svals, const int* __restrict__ vid,
                        unsigned* __restrict__ misc,
                        unsigned long long* __restrict__ cand) {
    const int V = (int)misc[4];
    const unsigned thr = misc[2];
    int i = blockIdx.x * blockDim.x + threadIdx.x;
    int stride = gridDim.x * blockDim.x;
    for (int v = i; v < V; v += stride) {
        unsigned bits = __float_as_uint(svals[v]);
        if (bits >= thr) {
            unsigned pos = atomicAdd(&misc[3], 1u);
            if (pos < CAND_CAP)
                cand[pos] = ((unsigned long long)bits << 32) |
                            (unsigned)(0xFFFFFFFFu - (unsigned)vid[v]);
        }
    }
}

// ---------------------------------------------------------------------------
// K7: exact fp32 rescore of candidates straight from emb/W1/b1/W2/b2.
// One block per candidate (grid-stride). Thread j computes h_j.
// ---------------------------------------------------------------------------
__global__ __launch_bounds__(256) void rescore(const float* __restrict__ emb,
                                               const float* __restrict__ W1,
                                               const float* __restrict__ b1,
                                               const float* __restrict__ W2,
                                               const float* __restrict__ b2,
                                               const int* __restrict__ eidx,
                                               const unsigned long long* __restrict__ cand,
                                               const unsigned* __restrict__ misc,
                                               unsigned long long* __restrict__ rescored,
                                               int E) {
    __shared__ float es[256], ed[256];
    __shared__ float red[256];
    const int C = (int)min(misc[3], (unsigned)CAND_CAP);
    const int is64 = (int)misc[0];
    const int t = threadIdx.x;
    for (int c = blockIdx.x; c < C; c += gridDim.x) {
        unsigned long long entry = cand[c];
        unsigned e = 0xFFFFFFFFu - (unsigned)(entry & 0xFFFFFFFFu);
        int src, dst;
        if (is64) {
            src = eidx[2 * (size_t)e];
            dst = eidx[2 * ((size_t)e + E)];
        } else {
            src = eidx[e];
            dst = eidx[e + E];
        }
        es[t] = emb[(size_t)src * 256 + t];
        ed[t] = emb[(size_t)dst * 256 + t];
        __syncthreads();
        float h = b1[t];
#pragma unroll 8
        for (int k = 0; k < 256; ++k) h += es[k] * W1[k * 256 + t];
#pragma unroll 8
        for (int k = 0; k < 256; ++k) h += ed[k] * W1[(256 + k) * 256 + t];
        red[t] = fmaxf(h, 0.f) * W2[t];
        __syncthreads();
        for (int s = 128; s; s >>= 1) {
            if (t < s) red[t] += red[t + s];
            __syncthreads();
        }
        if (t == 0) {
            float z = red[0] + b2[0];
            float sc = 1.0f / (1.0f + expf(-z));
            rescored[c] = ((unsigned long long)__float_as_uint(sc) << 32) |
                          (unsigned)(0xFFFFFFFFu - e);
        }
        __syncthreads();
    }
}

// ---------------------------------------------------------------------------
// K8: exact top-K over rescored candidates. key = bits<<32 | ~e.
// ---------------------------------------------------------------------------
__global__ void final_topk(unsigned long long* __restrict__ rescored,
                           const unsigned* __restrict__ misc,
                           const int* __restrict__ eidx,
                           float* __restrict__ out, int E) {
    __shared__ unsigned long long red[256];
    const int t = threadIdx.x;
    const int C = (int)min(misc[3], (unsigned)CAND_CAP);
    const int is64 = (int)misc[0];
    for (int r = 0; r < TOPK; ++r) {
        unsigned long long best = 0ull;
        for (int i = t; i < C; i += 256) {
            unsigned long long v = rescored[i];
            if (v > best) best = v;
        }
        red[t] = best;
        __syncthreads();
        for (int s = 128; s; s >>= 1) {
            if (t < s) {
                if (red[t + s] > red[t]) red[t] = red[t + s];
            }
            __syncthreads();
        }
        unsigned long long m = red[0];
        __syncthreads();
        for (int i = t; i < C; i += 256)
            if (rescored[i] == m) rescored[i] = 0ull;
        if (t == 0) {
            if (m != 0ull) {
                unsigned bits = (unsigned)(m >> 32);
                unsigned e = 0xFFFFFFFFu - (unsigned)(m & 0xFFFFFFFFu);
                int src, dst;
                if (is64) {
                    src = eidx[2 * (size_t)e];
                    dst = eidx[2 * ((size_t)e + E)];
                } else {
                    src = eidx[e];
                    dst = eidx[e + E];
                }
                out[r] = (float)src;
                out[TOPK + r] = (float)dst;
                out[2 * TOPK + r] = __uint_as_float(bits);
            } else {
                out[r] = -1.f;
                out[TOPK + r] = -1.f;
                out[2 * TOPK + r] = -1.f;
            }
        }
        __syncthreads();
    }
}

// ---------------------------------------------------------------------------
extern "C" void kernel_launch(void* const* d_in, const int* in_sizes, int n_in,
                              void* d_out, int out_size, void* d_ws, size_t ws_size,
                              hipStream_t stream) {
    const float* emb = (const float*)d_in[0];
    const float* W1  = (const float*)d_in[1];
    const float* b1  = (const float*)d_in[2];
    const float* W2  = (const float*)d_in[3];
    const float* b2  = (const float*)d_in[4];
    const int*   eidx = (const int*)d_in[5];

    const int M = in_sizes[0] / 256;           // 50000
    const int E = in_sizes[5] / 2;             // 800000
    const int Mpad = ((M + 127) / 128) * 128;  // 50048

    char* p = (char*)d_ws;
    auto alloc = [&](size_t bytes) {
        char* r = p;
        p += (bytes + 255) & ~(size_t)255;
        return r;
    };
    unsigned* A8f4 = (unsigned*)alloc((size_t)Mpad * 256 * 2);     // bf16 A-frags
    unsigned* Wcf4 = (unsigned*)alloc(256 * 512 * 2);              // bf16 B-frags
    unsigned char* C8 = (unsigned char*)alloc((size_t)Mpad * 512); // fp8 C
    float* svals = (float*)alloc((size_t)E * 4);
    int* vsrc = (int*)alloc((size_t)E * 4);
    int* vdst = (int*)alloc((size_t)E * 4);
    int* vid  = (int*)alloc((size_t)E * 4);
    unsigned* hist = (unsigned*)alloc(HIST_BINS * 4);
    unsigned long long* cand = (unsigned long long*)alloc(CAND_CAP * 8);
    unsigned long long* resc = (unsigned long long*)alloc(CAND_CAP * 8);
    unsigned* misc = (unsigned*)alloc(256);

    float* out = (float*)d_out;

    prep_kernel<<<64, 256, 0, stream>>>(W1, Wcf4, hist, misc, eidx);

    cvt_emb<<<Mpad / 16, 256, 0, stream>>>(emb, A8f4, M);

    dim3 ggrid(Mpad / 128, 4);
    gemm_frag<<<ggrid, 256, 0, stream>>>((const bf16x8*)A8f4, (const bf16x8*)Wcf4, b1, C8);

    filter_edges<<<1024, 256, 0, stream>>>(eidx, misc, vsrc, vdst, vid, E);

    edge_score_fp8<<<2048, 256, 0, stream>>>(C8, vsrc, vdst, W2, b2, svals, hist, misc);

    scan_hist<<<1, 256, 0, stream>>>(hist, misc);

    compact<<<1024, 256, 0, stream>>>(svals, vid, misc, cand);

    rescore<<<1024, 256, 0, stream>>>(emb, W1, b1, W2, b2, eidx, cand, misc, resc, E);

    final_topk<<<1, 256, 0, stream>>>(resc, misc, eidx, out, E);
}

// Round 5
// 356.786 us; speedup vs baseline: 5.5488x; 3.7797x over previous
//
#include <hip/hip_runtime.h>
#include <hip/hip_bf16.h>
#include <cstdint>

#define TOPK 50
#define CANDS 400          // rank margin for approx threshold
#define HIST_BINS 16384
#define CAND_CAP 16384

typedef __attribute__((ext_vector_type(8))) short bf16x8;
typedef __attribute__((ext_vector_type(4))) float f32x4;

__device__ __forceinline__ unsigned short f2bf(float f) {
    unsigned u = __float_as_uint(f);
    u += 0x7FFFu + ((u >> 16) & 1u);   // RNE
    return (unsigned short)(u >> 16);
}

// ---------------------------------------------------------------------------
// K0: prep — build Wc B-fragments (bf16, MFMA 16x16x32 layout), zero hist,
// detect int64 layout, zero counters.
// ---------------------------------------------------------------------------
__global__ __launch_bounds__(256) void prep_kernel(const float* __restrict__ W1,
                                                   unsigned* __restrict__ Wcf4,
                                                   unsigned* __restrict__ hist,
                                                   unsigned* __restrict__ misc,
                                                   const int* __restrict__ eidx) {
    int g = blockIdx.x * blockDim.x + threadIdx.x;   // 0..16383
    {
        int l = g & 63;
        int kt = (g >> 6) & 7;
        int nt = g >> 9;                 // 0..31
        int col = nt * 16 + (l & 15);
        int kb = kt * 32 + (l >> 4) * 8;
        unsigned short h[8];
#pragma unroll
        for (int j = 0; j < 8; ++j) {
            int k = kb + j;
            float f = (col < 256) ? W1[k * 256 + col] : W1[(256 + k) * 256 + (col - 256)];
            h[j] = f2bf(f);
        }
        unsigned* dst = Wcf4 + (size_t)g * 4;
        dst[0] = (unsigned)h[0] | ((unsigned)h[1] << 16);
        dst[1] = (unsigned)h[2] | ((unsigned)h[3] << 16);
        dst[2] = (unsigned)h[4] | ((unsigned)h[5] << 16);
        dst[3] = (unsigned)h[6] | ((unsigned)h[7] << 16);
    }
    if (g < HIST_BINS) hist[g] = 0;
    if (g == 0) {
        int allz = 1;
        for (int q = 0; q < 64; ++q)
            if (eidx[2 * q + 1] != 0) { allz = 0; break; }
        misc[0] = (unsigned)allz;  // 1 => int64 layout
        misc[2] = 0;               // threshold bits
        misc[3] = 0;               // candidate counter
        misc[4] = 0;               // valid-edge counter
    }
}

// ---------------------------------------------------------------------------
// K1: emb fp32 -> A-fragments bf16 (MFMA layout).
// ---------------------------------------------------------------------------
__global__ __launch_bounds__(256) void cvt_emb(const float* __restrict__ emb,
                                               unsigned* __restrict__ A8f4, int M) {
    __shared__ float sl[16][260];
    const int mt = blockIdx.x;
    const int t = threadIdx.x;
    {
        int row = t >> 4;
        int c0 = (t & 15) * 16;
        int gr = mt * 16 + row;
        float4 v0, v1, v2, v3;
        if (gr < M) {
            const float* sp = emb + (size_t)gr * 256 + c0;
            v0 = *(const float4*)(sp + 0);
            v1 = *(const float4*)(sp + 4);
            v2 = *(const float4*)(sp + 8);
            v3 = *(const float4*)(sp + 12);
        } else {
            v0 = v1 = v2 = v3 = make_float4(0.f, 0.f, 0.f, 0.f);
        }
        *(float4*)&sl[row][c0 + 0] = v0;
        *(float4*)&sl[row][c0 + 4] = v1;
        *(float4*)&sl[row][c0 + 8] = v2;
        *(float4*)&sl[row][c0 + 12] = v3;
    }
    __syncthreads();
    const int w = t >> 6;
    const int l = t & 63;
    const int r = l & 15;
    const int kb0 = (l >> 4) * 8;
#pragma unroll
    for (int it = 0; it < 2; ++it) {
        int kt = w + it * 4;
        int kb = kt * 32 + kb0;
        unsigned short h[8];
#pragma unroll
        for (int j = 0; j < 8; ++j) h[j] = f2bf(sl[r][kb + j]);
        unsigned* dst = A8f4 + ((size_t)(mt * 8 + kt) * 64 + l) * 4;
        dst[0] = (unsigned)h[0] | ((unsigned)h[1] << 16);
        dst[1] = (unsigned)h[2] | ((unsigned)h[3] << 16);
        dst[2] = (unsigned)h[4] | ((unsigned)h[5] << 16);
        dst[3] = (unsigned)h[6] | ((unsigned)h[7] << 16);
    }
}

// ---------------------------------------------------------------------------
// K2: no-LDS fragment GEMM. C = emb @ Wc (+b1 cols<256), stored fp8 e4m3.
// ---------------------------------------------------------------------------
__global__ __launch_bounds__(256) void gemm_frag(const bf16x8* __restrict__ A8v,
                                                 const bf16x8* __restrict__ Bv,
                                                 const float* __restrict__ b1,
                                                 unsigned char* __restrict__ C8) {
    const int bm = blockIdx.x;
    const int bn = blockIdx.y;
    const int t = threadIdx.x;
    const int w = t >> 6;
    const int l = t & 63;
    const int wm = w >> 1, wn = w & 1;

    f32x4 acc[4][4];
#pragma unroll
    for (int i = 0; i < 4; ++i)
#pragma unroll
        for (int j = 0; j < 4; ++j) acc[i][j] = (f32x4){0.f, 0.f, 0.f, 0.f};

    const int MT0 = bm * 8 + wm * 4;
    const int NT0 = bn * 8 + wn * 4;
#pragma unroll
    for (int kt = 0; kt < 8; ++kt) {
        bf16x8 af[4], bf_[4];
#pragma unroll
        for (int i = 0; i < 4; ++i) af[i] = A8v[(size_t)((MT0 + i) * 8 + kt) * 64 + l];
#pragma unroll
        for (int j = 0; j < 4; ++j) bf_[j] = Bv[(size_t)((NT0 + j) * 8 + kt) * 64 + l];
#pragma unroll
        for (int i = 0; i < 4; ++i)
#pragma unroll
            for (int j = 0; j < 4; ++j)
                acc[i][j] = __builtin_amdgcn_mfma_f32_16x16x32_bf16(af[i], bf_[j], acc[i][j], 0, 0, 0);
    }

    const int row0 = bm * 128 + wm * 64 + (l >> 4) * 4;
    const int col0 = bn * 128 + wn * 64 + (l & 15);
#pragma unroll
    for (int i = 0; i < 4; ++i) {
#pragma unroll
        for (int j = 0; j < 4; ++j) {
            int col = col0 + j * 16;
            float bias = (col < 256) ? b1[col] : 0.f;
#pragma unroll
            for (int r = 0; r < 4; ++r) {
                int row = row0 + i * 16 + r;
                float v = acc[i][j][r] + bias;
                int pk = __builtin_amdgcn_cvt_pk_fp8_f32(v, v, 0, false);
                C8[(size_t)row * 512 + col] = (unsigned char)(pk & 0xFF);
            }
        }
    }
}

// ---------------------------------------------------------------------------
// K3: filter — compact valid edges (src<dst) into dense vsrc/vdst/vid.
// ---------------------------------------------------------------------------
__global__ __launch_bounds__(256) void filter_edges(const int* __restrict__ eidx,
                                                    unsigned* __restrict__ misc,
                                                    int* __restrict__ vsrc,
                                                    int* __restrict__ vdst,
                                                    int* __restrict__ vid, int E) {
    const int is64 = (int)misc[0];
    const int lane = threadIdx.x & 63;
    int i = blockIdx.x * blockDim.x + threadIdx.x;
    int stride = gridDim.x * blockDim.x;
    for (int e = i; e < E; e += stride) {
        int s, d;
        if (is64) {
            int2 t0 = ((const int2*)eidx)[e];
            int2 t1 = ((const int2*)eidx)[(size_t)e + E];
            s = t0.x; d = t1.x;
        } else {
            s = eidx[e];
            d = eidx[e + E];
        }
        bool valid = s < d;
        unsigned long long mask = __ballot(valid);
        unsigned cnt = __popcll(mask);
        unsigned pfx = __popcll(mask & ((1ull << lane) - 1ull));
        unsigned basep = 0;
        if (lane == 0 && cnt) basep = atomicAdd(&misc[4], cnt);
        basep = __shfl(basep, 0, 64);
        if (valid) {
            int p = (int)(basep + pfx);
            vsrc[p] = s;
            vdst[p] = d;
            vid[p] = e;
        }
    }
}

// ---------------------------------------------------------------------------
// K4: fp8 edge scoring. 16 lanes/edge, 4 edges/wave. NO atomics.
// ---------------------------------------------------------------------------
__device__ __forceinline__ float dotq(unsigned a, unsigned b, float4 w) {
    float s;
    s  = fmaxf(__builtin_amdgcn_cvt_f32_fp8(a, 0) + __builtin_amdgcn_cvt_f32_fp8(b, 0), 0.f) * w.x;
    s += fmaxf(__builtin_amdgcn_cvt_f32_fp8(a, 1) + __builtin_amdgcn_cvt_f32_fp8(b, 1), 0.f) * w.y;
    s += fmaxf(__builtin_amdgcn_cvt_f32_fp8(a, 2) + __builtin_amdgcn_cvt_f32_fp8(b, 2), 0.f) * w.z;
    s += fmaxf(__builtin_amdgcn_cvt_f32_fp8(a, 3) + __builtin_amdgcn_cvt_f32_fp8(b, 3), 0.f) * w.w;
    return s;
}

__global__ __launch_bounds__(256) void edge_score_fp8(const unsigned char* __restrict__ C8,
                                                      const int* __restrict__ vsrc,
                                                      const int* __restrict__ vdst,
                                                      const float* __restrict__ W2,
                                                      const float* __restrict__ b2,
                                                      float* __restrict__ svals,
                                                      const unsigned* __restrict__ misc) {
    const int V = (int)misc[4];
    const int lane = threadIdx.x & 63;
    const int q = lane & 15;
    const int g = lane >> 4;
    const int wid = blockIdx.x * (blockDim.x >> 6) + (threadIdx.x >> 6);
    const int nw = gridDim.x * (blockDim.x >> 6);

    const float4 w0 = *(const float4*)&W2[q * 16 + 0];
    const float4 w1 = *(const float4*)&W2[q * 16 + 4];
    const float4 w2 = *(const float4*)&W2[q * 16 + 8];
    const float4 w3 = *(const float4*)&W2[q * 16 + 12];
    const float bb2 = b2[0];

    for (int base = wid * 4; base < V; base += nw * 4) {
        const int slot = base + g;
        const bool ok = slot < V;
        const int src = ok ? vsrc[slot] : 0;
        const int dst = ok ? vdst[slot] : 0;
        const uint4 ua = *(const uint4*)(C8 + (size_t)src * 512 + q * 16);
        const uint4 ub = *(const uint4*)(C8 + (size_t)dst * 512 + 256 + q * 16);
        float p = dotq(ua.x, ub.x, w0);
        p += dotq(ua.y, ub.y, w1);
        p += dotq(ua.z, ub.z, w2);
        p += dotq(ua.w, ub.w, w3);
        p += __shfl_xor(p, 1, 64);
        p += __shfl_xor(p, 2, 64);
        p += __shfl_xor(p, 4, 64);
        p += __shfl_xor(p, 8, 64);
        if (q == 0 && ok) {
            float z = p + bb2;
            float sc = 1.0f / (1.0f + expf(-z));
            svals[slot] = sc;
        }
    }
}

// ---------------------------------------------------------------------------
// K4b: histogram of score bits — per-block private LDS hist (64 KB), then
// merge nonzero bins to global (<=128 conflicting atomics per bin).
// ---------------------------------------------------------------------------
__global__ __launch_bounds__(256) void hist_kernel(const float* __restrict__ svals,
                                                   const unsigned* __restrict__ misc,
                                                   unsigned* __restrict__ hist) {
    __shared__ unsigned lh[HIST_BINS];
    const int V = (int)misc[4];
    const int t = threadIdx.x;
    for (int i = t; i < HIST_BINS; i += 256) lh[i] = 0;
    __syncthreads();
    int i = blockIdx.x * blockDim.x + t;
    int stride = gridDim.x * blockDim.x;
    for (int v = i; v < V; v += stride)
        atomicAdd(&lh[__float_as_uint(svals[v]) >> 16], 1u);
    __syncthreads();
    for (int b = t; b < HIST_BINS; b += 256) {
        unsigned c = lh[b];
        if (c) atomicAdd(&hist[b], c);
    }
}

// ---------------------------------------------------------------------------
// K5: scan histogram from top — threshold bin containing approx rank CANDS
// ---------------------------------------------------------------------------
__global__ void scan_hist(const unsigned* __restrict__ hist, unsigned* __restrict__ misc) {
    __shared__ unsigned chunk[256];
    int t = threadIdx.x;
    unsigned s = 0;
    for (int i = 0; i < 64; ++i) s += hist[t * 64 + i];
    chunk[t] = s;
    __syncthreads();
    if (t == 0) {
        unsigned cum = 0;
        int c;
        unsigned thr = 0;
        for (c = 255; c >= 0; --c) {
            if (cum + chunk[c] >= CANDS) break;
            cum += chunk[c];
        }
        if (c >= 0) {
            for (int b = c * 64 + 63; b >= c * 64; --b) {
                cum += hist[b];
                if (cum >= CANDS) { thr = ((unsigned)b) << 16; break; }
            }
        }
        misc[2] = thr;
    }
}

// ---------------------------------------------------------------------------
// K6: compact candidates (approx score bits >= threshold)
// ---------------------------------------------------------------------------
__global__ void compact(const float* __restrict__ svals, const int* __restrict__ vid,
                        unsigned* __restrict__ misc,
                        unsigned long long* __restrict__ cand) {
    const int V = (int)misc[4];
    const unsigned thr = misc[2];
    int i = blockIdx.x * blockDim.x + threadIdx.x;
    int stride = gridDim.x * blockDim.x;
    for (int v = i; v < V; v += stride) {
        unsigned bits = __float_as_uint(svals[v]);
        if (bits >= thr) {
            unsigned pos = atomicAdd(&misc[3], 1u);
            if (pos < CAND_CAP)
                cand[pos] = ((unsigned long long)bits << 32) |
                            (unsigned)(0xFFFFFFFFu - (unsigned)vid[v]);
        }
    }
}

// ---------------------------------------------------------------------------
// K7: exact fp32 rescore of candidates from emb/W1/b1/W2/b2.
// ---------------------------------------------------------------------------
__global__ __launch_bounds__(256) void rescore(const float* __restrict__ emb,
                                               const float* __restrict__ W1,
                                               const float* __restrict__ b1,
                                               const float* __restrict__ W2,
                                               const float* __restrict__ b2,
                                               const int* __restrict__ eidx,
                                               const unsigned long long* __restrict__ cand,
                                               const unsigned* __restrict__ misc,
                                               unsigned long long* __restrict__ rescored,
                                               int E) {
    __shared__ float es[256], ed[256];
    __shared__ float red[256];
    const int C = (int)min(misc[3], (unsigned)CAND_CAP);
    const int is64 = (int)misc[0];
    const int t = threadIdx.x;
    for (int c = blockIdx.x; c < C; c += gridDim.x) {
        unsigned long long entry = cand[c];
        unsigned e = 0xFFFFFFFFu - (unsigned)(entry & 0xFFFFFFFFu);
        int src, dst;
        if (is64) {
            src = eidx[2 * (size_t)e];
            dst = eidx[2 * ((size_t)e + E)];
        } else {
            src = eidx[e];
            dst = eidx[e + E];
        }
        es[t] = emb[(size_t)src * 256 + t];
        ed[t] = emb[(size_t)dst * 256 + t];
        __syncthreads();
        float h = b1[t];
#pragma unroll 8
        for (int k = 0; k < 256; ++k) h += es[k] * W1[k * 256 + t];
#pragma unroll 8
        for (int k = 0; k < 256; ++k) h += ed[k] * W1[(256 + k) * 256 + t];
        red[t] = fmaxf(h, 0.f) * W2[t];
        __syncthreads();
        for (int s = 128; s; s >>= 1) {
            if (t < s) red[t] += red[t + s];
            __syncthreads();
        }
        if (t == 0) {
            float z = red[0] + b2[0];
            float sc = 1.0f / (1.0f + expf(-z));
            rescored[c] = ((unsigned long long)__float_as_uint(sc) << 32) |
                          (unsigned)(0xFFFFFFFFu - e);
        }
        __syncthreads();
    }
}

// ---------------------------------------------------------------------------
// K8: exact top-K over rescored candidates. key = bits<<32 | ~e.
// ---------------------------------------------------------------------------
__global__ void final_topk(unsigned long long* __restrict__ rescored,
                           const unsigned* __restrict__ misc,
                           const int* __restrict__ eidx,
                           float* __restrict__ out, int E) {
    __shared__ unsigned long long red[256];
    const int t = threadIdx.x;
    const int C = (int)min(misc[3], (unsigned)CAND_CAP);
    const int is64 = (int)misc[0];
    for (int r = 0; r < TOPK; ++r) {
        unsigned long long best = 0ull;
        for (int i = t; i < C; i += 256) {
            unsigned long long v = rescored[i];
            if (v > best) best = v;
        }
        red[t] = best;
        __syncthreads();
        for (int s = 128; s; s >>= 1) {
            if (t < s) {
                if (red[t + s] > red[t]) red[t] = red[t + s];
            }
            __syncthreads();
        }
        unsigned long long m = red[0];
        __syncthreads();
        for (int i = t; i < C; i += 256)
            if (rescored[i] == m) rescored[i] = 0ull;
        if (t == 0) {
            if (m != 0ull) {
                unsigned bits = (unsigned)(m >> 32);
                unsigned e = 0xFFFFFFFFu - (unsigned)(m & 0xFFFFFFFFu);
                int src, dst;
                if (is64) {
                    src = eidx[2 * (size_t)e];
                    dst = eidx[2 * ((size_t)e + E)];
                } else {
                    src = eidx[e];
                    dst = eidx[e + E];
                }
                out[r] = (float)src;
                out[TOPK + r] = (float)dst;
                out[2 * TOPK + r] = __uint_as_float(bits);
            } else {
                out[r] = -1.f;
                out[TOPK + r] = -1.f;
                out[2 * TOPK + r] = -1.f;
            }
        }
        __syncthreads();
    }
}

// ---------------------------------------------------------------------------
extern "C" void kernel_launch(void* const* d_in, const int* in_sizes, int n_in,
                              void* d_out, int out_size, void* d_ws, size_t ws_size,
                              hipStream_t stream) {
    const float* emb = (const float*)d_in[0];
    const float* W1  = (const float*)d_in[1];
    const float* b1  = (const float*)d_in[2];
    const float* W2  = (const float*)d_in[3];
    const float* b2  = (const float*)d_in[4];
    const int*   eidx = (const int*)d_in[5];

    const int M = in_sizes[0] / 256;           // 50000
    const int E = in_sizes[5] / 2;             // 800000
    const int Mpad = ((M + 127) / 128) * 128;  // 50048

    char* p = (char*)d_ws;
    auto alloc = [&](size_t bytes) {
        char* r = p;
        p += (bytes + 255) & ~(size_t)255;
        return r;
    };
    unsigned* A8f4 = (unsigned*)alloc((size_t)Mpad * 256 * 2);     // bf16 A-frags
    unsigned* Wcf4 = (unsigned*)alloc(256 * 512 * 2);              // bf16 B-frags
    unsigned char* C8 = (unsigned char*)alloc((size_t)Mpad * 512); // fp8 C
    float* svals = (float*)alloc((size_t)E * 4);
    int* vsrc = (int*)alloc((size_t)E * 4);
    int* vdst = (int*)alloc((size_t)E * 4);
    int* vid  = (int*)alloc((size_t)E * 4);
    unsigned* hist = (unsigned*)alloc(HIST_BINS * 4);
    unsigned long long* cand = (unsigned long long*)alloc(CAND_CAP * 8);
    unsigned long long* resc = (unsigned long long*)alloc(CAND_CAP * 8);
    unsigned* misc = (unsigned*)alloc(256);

    float* out = (float*)d_out;

    prep_kernel<<<64, 256, 0, stream>>>(W1, Wcf4, hist, misc, eidx);

    cvt_emb<<<Mpad / 16, 256, 0, stream>>>(emb, A8f4, M);

    dim3 ggrid(Mpad / 128, 4);
    gemm_frag<<<ggrid, 256, 0, stream>>>((const bf16x8*)A8f4, (const bf16x8*)Wcf4, b1, C8);

    filter_edges<<<1024, 256, 0, stream>>>(eidx, misc, vsrc, vdst, vid, E);

    edge_score_fp8<<<2048, 256, 0, stream>>>(C8, vsrc, vdst, W2, b2, svals, misc);

    hist_kernel<<<128, 256, 0, stream>>>(svals, misc, hist);

    scan_hist<<<1, 256, 0, stream>>>(hist, misc);

    compact<<<1024, 256, 0, stream>>>(svals, vid, misc, cand);

    rescore<<<1024, 256, 0, stream>>>(emb, W1, b1, W2, b2, eidx, cand, misc, resc, E);

    final_topk<<<1, 256, 0, stream>>>(resc, misc, eidx, out, E);
}

// Round 6
// 224.102 us; speedup vs baseline: 8.8340x; 1.5921x over previous
//
#include <hip/hip_runtime.h>
#include <hip/hip_bf16.h>
#include <cstdint>

#define TOPK 50
#define CANDS 400          // rank margin for approx threshold
#define HIST_BINS 16384
#define CAND_CAP 16384
#define NFBLK 512          // filter blocks

typedef __attribute__((ext_vector_type(8))) short bf16x8;
typedef __attribute__((ext_vector_type(4))) float f32x4;

__device__ __forceinline__ unsigned short f2bf(float f) {
    unsigned u = __float_as_uint(f);
    u += 0x7FFFu + ((u >> 16) & 1u);   // RNE
    return (unsigned short)(u >> 16);
}

// ---------------------------------------------------------------------------
// K0: prep — build Wc B-fragments (bf16, MFMA 16x16x32 layout), zero hist,
// detect int64 layout, zero counters.
// ---------------------------------------------------------------------------
__global__ __launch_bounds__(256) void prep_kernel(const float* __restrict__ W1,
                                                   unsigned* __restrict__ Wcf4,
                                                   unsigned* __restrict__ hist,
                                                   unsigned* __restrict__ misc,
                                                   const int* __restrict__ eidx) {
    int g = blockIdx.x * blockDim.x + threadIdx.x;   // 0..16383
    {
        int l = g & 63;
        int kt = (g >> 6) & 7;
        int nt = g >> 9;                 // 0..31
        int col = nt * 16 + (l & 15);
        int kb = kt * 32 + (l >> 4) * 8;
        unsigned short h[8];
#pragma unroll
        for (int j = 0; j < 8; ++j) {
            int k = kb + j;
            float f = (col < 256) ? W1[k * 256 + col] : W1[(256 + k) * 256 + (col - 256)];
            h[j] = f2bf(f);
        }
        unsigned* dst = Wcf4 + (size_t)g * 4;
        dst[0] = (unsigned)h[0] | ((unsigned)h[1] << 16);
        dst[1] = (unsigned)h[2] | ((unsigned)h[3] << 16);
        dst[2] = (unsigned)h[4] | ((unsigned)h[5] << 16);
        dst[3] = (unsigned)h[6] | ((unsigned)h[7] << 16);
    }
    if (g < HIST_BINS) hist[g] = 0;
    if (g == 0) {
        int allz = 1;
        for (int q = 0; q < 64; ++q)
            if (eidx[2 * q + 1] != 0) { allz = 0; break; }
        misc[0] = (unsigned)allz;  // 1 => int64 layout
        misc[2] = 0;               // threshold bits
        misc[3] = 0;               // candidate counter
        misc[4] = 0;               // valid-edge counter
    }
}

// ---------------------------------------------------------------------------
// K1: emb fp32 -> A-fragments bf16 (MFMA layout).
// ---------------------------------------------------------------------------
__global__ __launch_bounds__(256) void cvt_emb(const float* __restrict__ emb,
                                               unsigned* __restrict__ A8f4, int M) {
    __shared__ float sl[16][260];
    const int mt = blockIdx.x;
    const int t = threadIdx.x;
    {
        int row = t >> 4;
        int c0 = (t & 15) * 16;
        int gr = mt * 16 + row;
        float4 v0, v1, v2, v3;
        if (gr < M) {
            const float* sp = emb + (size_t)gr * 256 + c0;
            v0 = *(const float4*)(sp + 0);
            v1 = *(const float4*)(sp + 4);
            v2 = *(const float4*)(sp + 8);
            v3 = *(const float4*)(sp + 12);
        } else {
            v0 = v1 = v2 = v3 = make_float4(0.f, 0.f, 0.f, 0.f);
        }
        *(float4*)&sl[row][c0 + 0] = v0;
        *(float4*)&sl[row][c0 + 4] = v1;
        *(float4*)&sl[row][c0 + 8] = v2;
        *(float4*)&sl[row][c0 + 12] = v3;
    }
    __syncthreads();
    const int w = t >> 6;
    const int l = t & 63;
    const int r = l & 15;
    const int kb0 = (l >> 4) * 8;
#pragma unroll
    for (int it = 0; it < 2; ++it) {
        int kt = w + it * 4;
        int kb = kt * 32 + kb0;
        unsigned short h[8];
#pragma unroll
        for (int j = 0; j < 8; ++j) h[j] = f2bf(sl[r][kb + j]);
        unsigned* dst = A8f4 + ((size_t)(mt * 8 + kt) * 64 + l) * 4;
        dst[0] = (unsigned)h[0] | ((unsigned)h[1] << 16);
        dst[1] = (unsigned)h[2] | ((unsigned)h[3] << 16);
        dst[2] = (unsigned)h[4] | ((unsigned)h[5] << 16);
        dst[3] = (unsigned)h[6] | ((unsigned)h[7] << 16);
    }
}

// ---------------------------------------------------------------------------
// K2: no-LDS fragment GEMM. C = emb @ Wc (+b1 cols<256), stored fp8 e4m3.
// ---------------------------------------------------------------------------
__global__ __launch_bounds__(256) void gemm_frag(const bf16x8* __restrict__ A8v,
                                                 const bf16x8* __restrict__ Bv,
                                                 const float* __restrict__ b1,
                                                 unsigned char* __restrict__ C8) {
    const int bm = blockIdx.x;
    const int bn = blockIdx.y;
    const int t = threadIdx.x;
    const int w = t >> 6;
    const int l = t & 63;
    const int wm = w >> 1, wn = w & 1;

    f32x4 acc[4][4];
#pragma unroll
    for (int i = 0; i < 4; ++i)
#pragma unroll
        for (int j = 0; j < 4; ++j) acc[i][j] = (f32x4){0.f, 0.f, 0.f, 0.f};

    const int MT0 = bm * 8 + wm * 4;
    const int NT0 = bn * 8 + wn * 4;
#pragma unroll
    for (int kt = 0; kt < 8; ++kt) {
        bf16x8 af[4], bf_[4];
#pragma unroll
        for (int i = 0; i < 4; ++i) af[i] = A8v[(size_t)((MT0 + i) * 8 + kt) * 64 + l];
#pragma unroll
        for (int j = 0; j < 4; ++j) bf_[j] = Bv[(size_t)((NT0 + j) * 8 + kt) * 64 + l];
#pragma unroll
        for (int i = 0; i < 4; ++i)
#pragma unroll
            for (int j = 0; j < 4; ++j)
                acc[i][j] = __builtin_amdgcn_mfma_f32_16x16x32_bf16(af[i], bf_[j], acc[i][j], 0, 0, 0);
    }

    const int row0 = bm * 128 + wm * 64 + (l >> 4) * 4;
    const int col0 = bn * 128 + wn * 64 + (l & 15);
#pragma unroll
    for (int i = 0; i < 4; ++i) {
#pragma unroll
        for (int j = 0; j < 4; ++j) {
            int col = col0 + j * 16;
            float bias = (col < 256) ? b1[col] : 0.f;
#pragma unroll
            for (int r = 0; r < 4; ++r) {
                int row = row0 + i * 16 + r;
                float v = acc[i][j][r] + bias;
                int pk = __builtin_amdgcn_cvt_pk_fp8_f32(v, v, 0, false);
                C8[(size_t)row * 512 + col] = (unsigned char)(pk & 0xFF);
            }
        }
    }
}

// ---------------------------------------------------------------------------
// K3a: count valid edges per block chunk (no atomics).
// ---------------------------------------------------------------------------
__global__ __launch_bounds__(256) void count_valid(const int* __restrict__ eidx,
                                                   const unsigned* __restrict__ misc,
                                                   unsigned* __restrict__ bcount, int E) {
    const int is64 = (int)misc[0];
    const int chunk = (E + gridDim.x - 1) / gridDim.x;
    const int lo = blockIdx.x * chunk;
    const int hi = min(E, lo + chunk);
    unsigned cnt = 0;
    for (int e = lo + threadIdx.x; e < hi; e += blockDim.x) {
        int s, d;
        if (is64) {
            s = ((const int2*)eidx)[e].x;
            d = ((const int2*)eidx)[(size_t)e + E].x;
        } else {
            s = eidx[e];
            d = eidx[e + E];
        }
        cnt += (s < d);
    }
#pragma unroll
    for (int off = 32; off; off >>= 1) cnt += __shfl_xor(cnt, off, 64);
    __shared__ unsigned wsum[4];
    if ((threadIdx.x & 63) == 0) wsum[threadIdx.x >> 6] = cnt;
    __syncthreads();
    if (threadIdx.x == 0)
        bcount[blockIdx.x] = wsum[0] + wsum[1] + wsum[2] + wsum[3];
}

// ---------------------------------------------------------------------------
// K3b: exclusive scan of NFBLK block counts -> boffset; total -> misc[4].
// ---------------------------------------------------------------------------
__global__ __launch_bounds__(256) void scan_blocks(const unsigned* __restrict__ bcount,
                                                   unsigned* __restrict__ boffset,
                                                   unsigned* __restrict__ misc) {
    __shared__ unsigned sc[256];
    const int t = threadIdx.x;
    unsigned a = bcount[2 * t], b = bcount[2 * t + 1];
    sc[t] = a + b;
    __syncthreads();
    for (int off = 1; off < 256; off <<= 1) {
        unsigned v = (t >= off) ? sc[t - off] : 0u;
        __syncthreads();
        sc[t] += v;
        __syncthreads();
    }
    unsigned excl = sc[t] - (a + b);
    boffset[2 * t] = excl;
    boffset[2 * t + 1] = excl + a;
    if (t == 255) misc[4] = sc[255];
}

// ---------------------------------------------------------------------------
// K3c: write compacted valid edges at boffset[b] + intra-block prefix.
// Disjoint ranges per block, zero atomics, deterministic.
// ---------------------------------------------------------------------------
__global__ __launch_bounds__(256) void write_valid(const int* __restrict__ eidx,
                                                   const unsigned* __restrict__ misc,
                                                   const unsigned* __restrict__ boffset,
                                                   int* __restrict__ vsrc,
                                                   int* __restrict__ vdst,
                                                   int* __restrict__ vid, int E) {
    const int is64 = (int)misc[0];
    const int chunk = (E + gridDim.x - 1) / gridDim.x;
    const int lo = blockIdx.x * chunk;
    const int hi = min(E, lo + chunk);
    const int lane = threadIdx.x & 63;
    const int w = threadIdx.x >> 6;
    __shared__ unsigned wcnt[4];
    unsigned running = boffset[blockIdx.x];
    for (int base = lo; base < hi; base += blockDim.x) {
        int e = base + threadIdx.x;
        bool valid = false;
        int s = 0, d = 0;
        if (e < hi) {
            if (is64) {
                s = ((const int2*)eidx)[e].x;
                d = ((const int2*)eidx)[(size_t)e + E].x;
            } else {
                s = eidx[e];
                d = eidx[e + E];
            }
            valid = s < d;
        }
        unsigned long long m = __ballot(valid);
        unsigned pfx = __popcll(m & ((1ull << lane) - 1ull));
        if (lane == 0) wcnt[w] = __popcll(m);
        __syncthreads();
        unsigned wbase = running;
        for (int i = 0; i < w; ++i) wbase += wcnt[i];
        if (valid) {
            unsigned p = wbase + pfx;
            vsrc[p] = s;
            vdst[p] = d;
            vid[p] = e;
        }
        unsigned tot = wcnt[0] + wcnt[1] + wcnt[2] + wcnt[3];
        __syncthreads();
        running += tot;
    }
}

// ---------------------------------------------------------------------------
// K4: fp8 edge scoring. 16 lanes/edge, 4 edges/wave. NO atomics.
// ---------------------------------------------------------------------------
__device__ __forceinline__ float dotq(unsigned a, unsigned b, float4 w) {
    float s;
    s  = fmaxf(__builtin_amdgcn_cvt_f32_fp8(a, 0) + __builtin_amdgcn_cvt_f32_fp8(b, 0), 0.f) * w.x;
    s += fmaxf(__builtin_amdgcn_cvt_f32_fp8(a, 1) + __builtin_amdgcn_cvt_f32_fp8(b, 1), 0.f) * w.y;
    s += fmaxf(__builtin_amdgcn_cvt_f32_fp8(a, 2) + __builtin_amdgcn_cvt_f32_fp8(b, 2), 0.f) * w.z;
    s += fmaxf(__builtin_amdgcn_cvt_f32_fp8(a, 3) + __builtin_amdgcn_cvt_f32_fp8(b, 3), 0.f) * w.w;
    return s;
}

__global__ __launch_bounds__(256) void edge_score_fp8(const unsigned char* __restrict__ C8,
                                                      const int* __restrict__ vsrc,
                                                      const int* __restrict__ vdst,
                                                      const float* __restrict__ W2,
                                                      const float* __restrict__ b2,
                                                      float* __restrict__ svals,
                                                      const unsigned* __restrict__ misc) {
    const int V = (int)misc[4];
    const int lane = threadIdx.x & 63;
    const int q = lane & 15;
    const int g = lane >> 4;
    const int wid = blockIdx.x * (blockDim.x >> 6) + (threadIdx.x >> 6);
    const int nw = gridDim.x * (blockDim.x >> 6);

    const float4 w0 = *(const float4*)&W2[q * 16 + 0];
    const float4 w1 = *(const float4*)&W2[q * 16 + 4];
    const float4 w2 = *(const float4*)&W2[q * 16 + 8];
    const float4 w3 = *(const float4*)&W2[q * 16 + 12];
    const float bb2 = b2[0];

    for (int base = wid * 4; base < V; base += nw * 4) {
        const int slot = base + g;
        const bool ok = slot < V;
        const int src = ok ? vsrc[slot] : 0;
        const int dst = ok ? vdst[slot] : 0;
        const uint4 ua = *(const uint4*)(C8 + (size_t)src * 512 + q * 16);
        const uint4 ub = *(const uint4*)(C8 + (size_t)dst * 512 + 256 + q * 16);
        float p = dotq(ua.x, ub.x, w0);
        p += dotq(ua.y, ub.y, w1);
        p += dotq(ua.z, ub.z, w2);
        p += dotq(ua.w, ub.w, w3);
        p += __shfl_xor(p, 1, 64);
        p += __shfl_xor(p, 2, 64);
        p += __shfl_xor(p, 4, 64);
        p += __shfl_xor(p, 8, 64);
        if (q == 0 && ok) {
            float z = p + bb2;
            float sc = 1.0f / (1.0f + expf(-z));
            svals[slot] = sc;
        }
    }
}

// ---------------------------------------------------------------------------
// K4b: histogram — per-block private LDS hist, then merge nonzero bins.
// ---------------------------------------------------------------------------
__global__ __launch_bounds__(256) void hist_kernel(const float* __restrict__ svals,
                                                   const unsigned* __restrict__ misc,
                                                   unsigned* __restrict__ hist) {
    __shared__ unsigned lh[HIST_BINS];
    const int V = (int)misc[4];
    const int t = threadIdx.x;
    for (int i = t; i < HIST_BINS; i += 256) lh[i] = 0;
    __syncthreads();
    int i = blockIdx.x * blockDim.x + t;
    int stride = gridDim.x * blockDim.x;
    for (int v = i; v < V; v += stride)
        atomicAdd(&lh[__float_as_uint(svals[v]) >> 16], 1u);
    __syncthreads();
    for (int b = t; b < HIST_BINS; b += 256) {
        unsigned c = lh[b];
        if (c) atomicAdd(&hist[b], c);
    }
}

// ---------------------------------------------------------------------------
// K5: scan histogram from top — threshold bin containing approx rank CANDS
// ---------------------------------------------------------------------------
__global__ void scan_hist(const unsigned* __restrict__ hist, unsigned* __restrict__ misc) {
    __shared__ unsigned chunk[256];
    int t = threadIdx.x;
    unsigned s = 0;
    for (int i = 0; i < 64; ++i) s += hist[t * 64 + i];
    chunk[t] = s;
    __syncthreads();
    if (t == 0) {
        unsigned cum = 0;
        int c;
        unsigned thr = 0;
        for (c = 255; c >= 0; --c) {
            if (cum + chunk[c] >= CANDS) break;
            cum += chunk[c];
        }
        if (c >= 0) {
            for (int b = c * 64 + 63; b >= c * 64; --b) {
                cum += hist[b];
                if (cum >= CANDS) { thr = ((unsigned)b) << 16; break; }
            }
        }
        misc[2] = thr;
    }
}

// ---------------------------------------------------------------------------
// K6: compact candidates (approx score bits >= threshold)
// ---------------------------------------------------------------------------
__global__ void compact(const float* __restrict__ svals, const int* __restrict__ vid,
                        unsigned* __restrict__ misc,
                        unsigned long long* __restrict__ cand) {
    const int V = (int)misc[4];
    const unsigned thr = misc[2];
    int i = blockIdx.x * blockDim.x + threadIdx.x;
    int stride = gridDim.x * blockDim.x;
    for (int v = i; v < V; v += stride) {
        unsigned bits = __float_as_uint(svals[v]);
        if (bits >= thr) {
            unsigned pos = atomicAdd(&misc[3], 1u);
            if (pos < CAND_CAP)
                cand[pos] = ((unsigned long long)bits << 32) |
                            (unsigned)(0xFFFFFFFFu - (unsigned)vid[v]);
        }
    }
}

// ---------------------------------------------------------------------------
// K7: exact fp32 rescore of candidates from emb/W1/b1/W2/b2.
// ---------------------------------------------------------------------------
__global__ __launch_bounds__(256) void rescore(const float* __restrict__ emb,
                                               const float* __restrict__ W1,
                                               const float* __restrict__ b1,
                                               const float* __restrict__ W2,
                                               const float* __restrict__ b2,
                                               const int* __restrict__ eidx,
                                               const unsigned long long* __restrict__ cand,
                                               const unsigned* __restrict__ misc,
                                               unsigned long long* __restrict__ rescored,
                                               int E) {
    __shared__ float es[256], ed[256];
    __shared__ float red[256];
    const int C = (int)min(misc[3], (unsigned)CAND_CAP);
    const int is64 = (int)misc[0];
    const int t = threadIdx.x;
    for (int c = blockIdx.x; c < C; c += gridDim.x) {
        unsigned long long entry = cand[c];
        unsigned e = 0xFFFFFFFFu - (unsigned)(entry & 0xFFFFFFFFu);
        int src, dst;
        if (is64) {
            src = eidx[2 * (size_t)e];
            dst = eidx[2 * ((size_t)e + E)];
        } else {
            src = eidx[e];
            dst = eidx[e + E];
        }
        es[t] = emb[(size_t)src * 256 + t];
        ed[t] = emb[(size_t)dst * 256 + t];
        __syncthreads();
        float h = b1[t];
#pragma unroll 8
        for (int k = 0; k < 256; ++k) h += es[k] * W1[k * 256 + t];
#pragma unroll 8
        for (int k = 0; k < 256; ++k) h += ed[k] * W1[(256 + k) * 256 + t];
        red[t] = fmaxf(h, 0.f) * W2[t];
        __syncthreads();
        for (int s = 128; s; s >>= 1) {
            if (t < s) red[t] += red[t + s];
            __syncthreads();
        }
        if (t == 0) {
            float z = red[0] + b2[0];
            float sc = 1.0f / (1.0f + expf(-z));
            rescored[c] = ((unsigned long long)__float_as_uint(sc) << 32) |
                          (unsigned)(0xFFFFFFFFu - e);
        }
        __syncthreads();
    }
}

// ---------------------------------------------------------------------------
// K8: exact top-K over rescored candidates. key = bits<<32 | ~e.
// ---------------------------------------------------------------------------
__global__ void final_topk(unsigned long long* __restrict__ rescored,
                           const unsigned* __restrict__ misc,
                           const int* __restrict__ eidx,
                           float* __restrict__ out, int E) {
    __shared__ unsigned long long red[256];
    const int t = threadIdx.x;
    const int C = (int)min(misc[3], (unsigned)CAND_CAP);
    const int is64 = (int)misc[0];
    for (int r = 0; r < TOPK; ++r) {
        unsigned long long best = 0ull;
        for (int i = t; i < C; i += 256) {
            unsigned long long v = rescored[i];
            if (v > best) best = v;
        }
        red[t] = best;
        __syncthreads();
        for (int s = 128; s; s >>= 1) {
            if (t < s) {
                if (red[t + s] > red[t]) red[t] = red[t + s];
            }
            __syncthreads();
        }
        unsigned long long m = red[0];
        __syncthreads();
        for (int i = t; i < C; i += 256)
            if (rescored[i] == m) rescored[i] = 0ull;
        if (t == 0) {
            if (m != 0ull) {
                unsigned bits = (unsigned)(m >> 32);
                unsigned e = 0xFFFFFFFFu - (unsigned)(m & 0xFFFFFFFFu);
                int src, dst;
                if (is64) {
                    src = eidx[2 * (size_t)e];
                    dst = eidx[2 * ((size_t)e + E)];
                } else {
                    src = eidx[e];
                    dst = eidx[e + E];
                }
                out[r] = (float)src;
                out[TOPK + r] = (float)dst;
                out[2 * TOPK + r] = __uint_as_float(bits);
            } else {
                out[r] = -1.f;
                out[TOPK + r] = -1.f;
                out[2 * TOPK + r] = -1.f;
            }
        }
        __syncthreads();
    }
}

// ---------------------------------------------------------------------------
extern "C" void kernel_launch(void* const* d_in, const int* in_sizes, int n_in,
                              void* d_out, int out_size, void* d_ws, size_t ws_size,
                              hipStream_t stream) {
    const float* emb = (const float*)d_in[0];
    const float* W1  = (const float*)d_in[1];
    const float* b1  = (const float*)d_in[2];
    const float* W2  = (const float*)d_in[3];
    const float* b2  = (const float*)d_in[4];
    const int*   eidx = (const int*)d_in[5];

    const int M = in_sizes[0] / 256;           // 50000
    const int E = in_sizes[5] / 2;             // 800000
    const int Mpad = ((M + 127) / 128) * 128;  // 50048

    char* p = (char*)d_ws;
    auto alloc = [&](size_t bytes) {
        char* r = p;
        p += (bytes + 255) & ~(size_t)255;
        return r;
    };
    unsigned* A8f4 = (unsigned*)alloc((size_t)Mpad * 256 * 2);     // bf16 A-frags
    unsigned* Wcf4 = (unsigned*)alloc(256 * 512 * 2);              // bf16 B-frags
    unsigned char* C8 = (unsigned char*)alloc((size_t)Mpad * 512); // fp8 C
    float* svals = (float*)alloc((size_t)E * 4);
    int* vsrc = (int*)alloc((size_t)E * 4);
    int* vdst = (int*)alloc((size_t)E * 4);
    int* vid  = (int*)alloc((size_t)E * 4);
    unsigned* hist = (unsigned*)alloc(HIST_BINS * 4);
    unsigned long long* cand = (unsigned long long*)alloc(CAND_CAP * 8);
    unsigned long long* resc = (unsigned long long*)alloc(CAND_CAP * 8);
    unsigned* bcount = (unsigned*)alloc(NFBLK * 4);
    unsigned* boffset = (unsigned*)alloc(NFBLK * 4);
    unsigned* misc = (unsigned*)alloc(256);

    float* out = (float*)d_out;

    prep_kernel<<<64, 256, 0, stream>>>(W1, Wcf4, hist, misc, eidx);

    cvt_emb<<<Mpad / 16, 256, 0, stream>>>(emb, A8f4, M);

    dim3 ggrid(Mpad / 128, 4);
    gemm_frag<<<ggrid, 256, 0, stream>>>((const bf16x8*)A8f4, (const bf16x8*)Wcf4, b1, C8);

    count_valid<<<NFBLK, 256, 0, stream>>>(eidx, misc, bcount, E);
    scan_blocks<<<1, 256, 0, stream>>>(bcount, boffset, misc);
    write_valid<<<NFBLK, 256, 0, stream>>>(eidx, misc, boffset, vsrc, vdst, vid, E);

    edge_score_fp8<<<2048, 256, 0, stream>>>(C8, vsrc, vdst, W2, b2, svals, misc);

    hist_kernel<<<128, 256, 0, stream>>>(svals, misc, hist);

    scan_hist<<<1, 256, 0, stream>>>(hist, misc);

    compact<<<1024, 256, 0, stream>>>(svals, vid, misc, cand);

    rescore<<<1024, 256, 0, stream>>>(emb, W1, b1, W2, b2, eidx, cand, misc, resc, E);

    final_topk<<<1, 256, 0, stream>>>(resc, misc, eidx, out, E);
}

// Round 8
// 167.239 us; speedup vs baseline: 11.8377x; 1.3400x over previous
//
#include <hip/hip_runtime.h>
#include <hip/hip_bf16.h>
#include <cstdint>

#define TOPK 50
#define CANDS 400          // rank margin for approx threshold
#define HIST_BINS 16384
#define CAND_CAP 16384
#define NFBLK 512          // filter blocks
#define SORT_CAP 8192      // LDS bitonic capacity

typedef __attribute__((ext_vector_type(8))) short bf16x8;
typedef __attribute__((ext_vector_type(4))) float f32x4;

__device__ __forceinline__ unsigned short f2bf(float f) {
    unsigned u = __float_as_uint(f);
    u += 0x7FFFu + ((u >> 16) & 1u);   // RNE
    return (unsigned short)(u >> 16);
}

// ---------------------------------------------------------------------------
// K0: prep — build Wc B-fragments (bf16, MFMA 16x16x32 layout), zero hist,
// detect int64 layout, zero counters.
// ---------------------------------------------------------------------------
__global__ __launch_bounds__(256) void prep_kernel(const float* __restrict__ W1,
                                                   unsigned* __restrict__ Wcf4,
                                                   unsigned* __restrict__ hist,
                                                   unsigned* __restrict__ misc,
                                                   const int* __restrict__ eidx) {
    int g = blockIdx.x * blockDim.x + threadIdx.x;   // 0..16383
    {
        int l = g & 63;
        int kt = (g >> 6) & 7;
        int nt = g >> 9;                 // 0..31
        int col = nt * 16 + (l & 15);
        int kb = kt * 32 + (l >> 4) * 8;
        unsigned short h[8];
#pragma unroll
        for (int j = 0; j < 8; ++j) {
            int k = kb + j;
            float f = (col < 256) ? W1[k * 256 + col] : W1[(256 + k) * 256 + (col - 256)];
            h[j] = f2bf(f);
        }
        unsigned* dst = Wcf4 + (size_t)g * 4;
        dst[0] = (unsigned)h[0] | ((unsigned)h[1] << 16);
        dst[1] = (unsigned)h[2] | ((unsigned)h[3] << 16);
        dst[2] = (unsigned)h[4] | ((unsigned)h[5] << 16);
        dst[3] = (unsigned)h[6] | ((unsigned)h[7] << 16);
    }
    if (g < HIST_BINS) hist[g] = 0;
    if (g == 0) {
        int allz = 1;
        for (int q = 0; q < 64; ++q)
            if (eidx[2 * q + 1] != 0) { allz = 0; break; }
        misc[0] = (unsigned)allz;  // 1 => int64 layout
        misc[2] = 0;               // threshold bits
        misc[3] = 0;               // candidate counter
        misc[4] = 0;               // valid-edge counter
    }
}

// ---------------------------------------------------------------------------
// K1: emb fp32 -> A-fragments bf16 (MFMA layout).
// ---------------------------------------------------------------------------
__global__ __launch_bounds__(256) void cvt_emb(const float* __restrict__ emb,
                                               unsigned* __restrict__ A8f4, int M) {
    __shared__ float sl[16][260];
    const int mt = blockIdx.x;
    const int t = threadIdx.x;
    {
        int row = t >> 4;
        int c0 = (t & 15) * 16;
        int gr = mt * 16 + row;
        float4 v0, v1, v2, v3;
        if (gr < M) {
            const float* sp = emb + (size_t)gr * 256 + c0;
            v0 = *(const float4*)(sp + 0);
            v1 = *(const float4*)(sp + 4);
            v2 = *(const float4*)(sp + 8);
            v3 = *(const float4*)(sp + 12);
        } else {
            v0 = v1 = v2 = v3 = make_float4(0.f, 0.f, 0.f, 0.f);
        }
        *(float4*)&sl[row][c0 + 0] = v0;
        *(float4*)&sl[row][c0 + 4] = v1;
        *(float4*)&sl[row][c0 + 8] = v2;
        *(float4*)&sl[row][c0 + 12] = v3;
    }
    __syncthreads();
    const int w = t >> 6;
    const int l = t & 63;
    const int r = l & 15;
    const int kb0 = (l >> 4) * 8;
#pragma unroll
    for (int it = 0; it < 2; ++it) {
        int kt = w + it * 4;
        int kb = kt * 32 + kb0;
        unsigned short h[8];
#pragma unroll
        for (int j = 0; j < 8; ++j) h[j] = f2bf(sl[r][kb + j]);
        unsigned* dst = A8f4 + ((size_t)(mt * 8 + kt) * 64 + l) * 4;
        dst[0] = (unsigned)h[0] | ((unsigned)h[1] << 16);
        dst[1] = (unsigned)h[2] | ((unsigned)h[3] << 16);
        dst[2] = (unsigned)h[4] | ((unsigned)h[5] << 16);
        dst[3] = (unsigned)h[6] | ((unsigned)h[7] << 16);
    }
}

// ---------------------------------------------------------------------------
// K2: no-LDS fragment GEMM. C = emb @ Wc (+b1 cols<256), stored fp8 e4m3.
// ---------------------------------------------------------------------------
__global__ __launch_bounds__(256) void gemm_frag(const bf16x8* __restrict__ A8v,
                                                 const bf16x8* __restrict__ Bv,
                                                 const float* __restrict__ b1,
                                                 unsigned char* __restrict__ C8) {
    const int bm = blockIdx.x;
    const int bn = blockIdx.y;
    const int t = threadIdx.x;
    const int w = t >> 6;
    const int l = t & 63;
    const int wm = w >> 1, wn = w & 1;

    f32x4 acc[4][4];
#pragma unroll
    for (int i = 0; i < 4; ++i)
#pragma unroll
        for (int j = 0; j < 4; ++j) acc[i][j] = (f32x4){0.f, 0.f, 0.f, 0.f};

    const int MT0 = bm * 8 + wm * 4;
    const int NT0 = bn * 8 + wn * 4;
#pragma unroll
    for (int kt = 0; kt < 8; ++kt) {
        bf16x8 af[4], bf_[4];
#pragma unroll
        for (int i = 0; i < 4; ++i) af[i] = A8v[(size_t)((MT0 + i) * 8 + kt) * 64 + l];
#pragma unroll
        for (int j = 0; j < 4; ++j) bf_[j] = Bv[(size_t)((NT0 + j) * 8 + kt) * 64 + l];
#pragma unroll
        for (int i = 0; i < 4; ++i)
#pragma unroll
            for (int j = 0; j < 4; ++j)
                acc[i][j] = __builtin_amdgcn_mfma_f32_16x16x32_bf16(af[i], bf_[j], acc[i][j], 0, 0, 0);
    }

    const int row0 = bm * 128 + wm * 64 + (l >> 4) * 4;
    const int col0 = bn * 128 + wn * 64 + (l & 15);
#pragma unroll
    for (int i = 0; i < 4; ++i) {
#pragma unroll
        for (int j = 0; j < 4; ++j) {
            int col = col0 + j * 16;
            float bias = (col < 256) ? b1[col] : 0.f;
#pragma unroll
            for (int r = 0; r < 4; ++r) {
                int row = row0 + i * 16 + r;
                float v = acc[i][j][r] + bias;
                int pk = __builtin_amdgcn_cvt_pk_fp8_f32(v, v, 0, false);
                C8[(size_t)row * 512 + col] = (unsigned char)(pk & 0xFF);
            }
        }
    }
}

// ---------------------------------------------------------------------------
// K3a: count valid edges per block chunk (no atomics).
// ---------------------------------------------------------------------------
__global__ __launch_bounds__(256) void count_valid(const int* __restrict__ eidx,
                                                   const unsigned* __restrict__ misc,
                                                   unsigned* __restrict__ bcount, int E) {
    const int is64 = (int)misc[0];
    const int chunk = (E + gridDim.x - 1) / gridDim.x;
    const int lo = blockIdx.x * chunk;
    const int hi = min(E, lo + chunk);
    unsigned cnt = 0;
    for (int e = lo + threadIdx.x; e < hi; e += blockDim.x) {
        int s, d;
        if (is64) {
            s = ((const int2*)eidx)[e].x;
            d = ((const int2*)eidx)[(size_t)e + E].x;
        } else {
            s = eidx[e];
            d = eidx[e + E];
        }
        cnt += (s < d);
    }
#pragma unroll
    for (int off = 32; off; off >>= 1) cnt += __shfl_xor(cnt, off, 64);
    __shared__ unsigned wsum[4];
    if ((threadIdx.x & 63) == 0) wsum[threadIdx.x >> 6] = cnt;
    __syncthreads();
    if (threadIdx.x == 0)
        bcount[blockIdx.x] = wsum[0] + wsum[1] + wsum[2] + wsum[3];
}

// ---------------------------------------------------------------------------
// K3b: exclusive scan of NFBLK block counts -> boffset; total -> misc[4].
// ---------------------------------------------------------------------------
__global__ __launch_bounds__(256) void scan_blocks(const unsigned* __restrict__ bcount,
                                                   unsigned* __restrict__ boffset,
                                                   unsigned* __restrict__ misc) {
    __shared__ unsigned sc[256];
    const int t = threadIdx.x;
    unsigned a = bcount[2 * t], b = bcount[2 * t + 1];
    sc[t] = a + b;
    __syncthreads();
    for (int off = 1; off < 256; off <<= 1) {
        unsigned v = (t >= off) ? sc[t - off] : 0u;
        __syncthreads();
        sc[t] += v;
        __syncthreads();
    }
    unsigned excl = sc[t] - (a + b);
    boffset[2 * t] = excl;
    boffset[2 * t + 1] = excl + a;
    if (t == 255) misc[4] = sc[255];
}

// ---------------------------------------------------------------------------
// K3c: write compacted valid edges at boffset[b] + intra-block prefix.
// ---------------------------------------------------------------------------
__global__ __launch_bounds__(256) void write_valid(const int* __restrict__ eidx,
                                                   const unsigned* __restrict__ misc,
                                                   const unsigned* __restrict__ boffset,
                                                   int* __restrict__ vsrc,
                                                   int* __restrict__ vdst,
                                                   int* __restrict__ vid, int E) {
    const int is64 = (int)misc[0];
    const int chunk = (E + gridDim.x - 1) / gridDim.x;
    const int lo = blockIdx.x * chunk;
    const int hi = min(E, lo + chunk);
    const int lane = threadIdx.x & 63;
    const int w = threadIdx.x >> 6;
    __shared__ unsigned wcnt[4];
    unsigned running = boffset[blockIdx.x];
    for (int base = lo; base < hi; base += blockDim.x) {
        int e = base + threadIdx.x;
        bool valid = false;
        int s = 0, d = 0;
        if (e < hi) {
            if (is64) {
                s = ((const int2*)eidx)[e].x;
                d = ((const int2*)eidx)[(size_t)e + E].x;
            } else {
                s = eidx[e];
                d = eidx[e + E];
            }
            valid = s < d;
        }
        unsigned long long m = __ballot(valid);
        unsigned pfx = __popcll(m & ((1ull << lane) - 1ull));
        if (lane == 0) wcnt[w] = __popcll(m);
        __syncthreads();
        unsigned wbase = running;
        for (int i = 0; i < w; ++i) wbase += wcnt[i];
        if (valid) {
            unsigned p = wbase + pfx;
            vsrc[p] = s;
            vdst[p] = d;
            vid[p] = e;
        }
        unsigned tot = wcnt[0] + wcnt[1] + wcnt[2] + wcnt[3];
        __syncthreads();
        running += tot;
    }
}

// ---------------------------------------------------------------------------
// K4: fp8 edge scoring. 16 lanes/edge, 4 edges/wave. NO atomics.
// ---------------------------------------------------------------------------
__device__ __forceinline__ float dotq(unsigned a, unsigned b, float4 w) {
    float s;
    s  = fmaxf(__builtin_amdgcn_cvt_f32_fp8(a, 0) + __builtin_amdgcn_cvt_f32_fp8(b, 0), 0.f) * w.x;
    s += fmaxf(__builtin_amdgcn_cvt_f32_fp8(a, 1) + __builtin_amdgcn_cvt_f32_fp8(b, 1), 0.f) * w.y;
    s += fmaxf(__builtin_amdgcn_cvt_f32_fp8(a, 2) + __builtin_amdgcn_cvt_f32_fp8(b, 2), 0.f) * w.z;
    s += fmaxf(__builtin_amdgcn_cvt_f32_fp8(a, 3) + __builtin_amdgcn_cvt_f32_fp8(b, 3), 0.f) * w.w;
    return s;
}

__global__ __launch_bounds__(256) void edge_score_fp8(const unsigned char* __restrict__ C8,
                                                      const int* __restrict__ vsrc,
                                                      const int* __restrict__ vdst,
                                                      const float* __restrict__ W2,
                                                      const float* __restrict__ b2,
                                                      float* __restrict__ svals,
                                                      const unsigned* __restrict__ misc) {
    const int V = (int)misc[4];
    const int lane = threadIdx.x & 63;
    const int q = lane & 15;
    const int g = lane >> 4;
    const int wid = blockIdx.x * (blockDim.x >> 6) + (threadIdx.x >> 6);
    const int nw = gridDim.x * (blockDim.x >> 6);

    const float4 w0 = *(const float4*)&W2[q * 16 + 0];
    const float4 w1 = *(const float4*)&W2[q * 16 + 4];
    const float4 w2 = *(const float4*)&W2[q * 16 + 8];
    const float4 w3 = *(const float4*)&W2[q * 16 + 12];
    const float bb2 = b2[0];

    for (int base = wid * 4; base < V; base += nw * 4) {
        const int slot = base + g;
        const bool ok = slot < V;
        const int src = ok ? vsrc[slot] : 0;
        const int dst = ok ? vdst[slot] : 0;
        const uint4 ua = *(const uint4*)(C8 + (size_t)src * 512 + q * 16);
        const uint4 ub = *(const uint4*)(C8 + (size_t)dst * 512 + 256 + q * 16);
        float p = dotq(ua.x, ub.x, w0);
        p += dotq(ua.y, ub.y, w1);
        p += dotq(ua.z, ub.z, w2);
        p += dotq(ua.w, ub.w, w3);
        p += __shfl_xor(p, 1, 64);
        p += __shfl_xor(p, 2, 64);
        p += __shfl_xor(p, 4, 64);
        p += __shfl_xor(p, 8, 64);
        if (q == 0 && ok) {
            float z = p + bb2;
            float sc = 1.0f / (1.0f + expf(-z));
            svals[slot] = sc;
        }
    }
}

// ---------------------------------------------------------------------------
// K4b: histogram — per-block private LDS hist, then merge nonzero bins.
// ---------------------------------------------------------------------------
__global__ __launch_bounds__(256) void hist_kernel(const float* __restrict__ svals,
                                                   const unsigned* __restrict__ misc,
                                                   unsigned* __restrict__ hist) {
    __shared__ unsigned lh[HIST_BINS];
    const int V = (int)misc[4];
    const int t = threadIdx.x;
    for (int i = t; i < HIST_BINS; i += 256) lh[i] = 0;
    __syncthreads();
    int i = blockIdx.x * blockDim.x + t;
    int stride = gridDim.x * blockDim.x;
    for (int v = i; v < V; v += stride)
        atomicAdd(&lh[__float_as_uint(svals[v]) >> 16], 1u);
    __syncthreads();
    for (int b = t; b < HIST_BINS; b += 256) {
        unsigned c = lh[b];
        if (c) atomicAdd(&hist[b], c);
    }
}

// ---------------------------------------------------------------------------
// K5: scan histogram from top — threshold bin containing approx rank CANDS
// ---------------------------------------------------------------------------
__global__ void scan_hist(const unsigned* __restrict__ hist, unsigned* __restrict__ misc) {
    __shared__ unsigned chunk[256];
    int t = threadIdx.x;
    unsigned s = 0;
    for (int i = 0; i < 64; ++i) s += hist[t * 64 + i];
    chunk[t] = s;
    __syncthreads();
    if (t == 0) {
        unsigned cum = 0;
        int c;
        unsigned thr = 0;
        for (c = 255; c >= 0; --c) {
            if (cum + chunk[c] >= CANDS) break;
            cum += chunk[c];
        }
        if (c >= 0) {
            for (int b = c * 64 + 63; b >= c * 64; --b) {
                cum += hist[b];
                if (cum >= CANDS) { thr = ((unsigned)b) << 16; break; }
            }
        }
        misc[2] = thr;
    }
}

// ---------------------------------------------------------------------------
// K6: compact candidates (approx score bits >= threshold)
// ---------------------------------------------------------------------------
__global__ void compact(const float* __restrict__ svals, const int* __restrict__ vid,
                        unsigned* __restrict__ misc,
                        unsigned long long* __restrict__ cand) {
    const int V = (int)misc[4];
    const unsigned thr = misc[2];
    int i = blockIdx.x * blockDim.x + threadIdx.x;
    int stride = gridDim.x * blockDim.x;
    for (int v = i; v < V; v += stride) {
        unsigned bits = __float_as_uint(svals[v]);
        if (bits >= thr) {
            unsigned pos = atomicAdd(&misc[3], 1u);
            if (pos < CAND_CAP)
                cand[pos] = ((unsigned long long)bits << 32) |
                            (unsigned)(0xFFFFFFFFu - (unsigned)vid[v]);
        }
    }
}

// ---------------------------------------------------------------------------
// K7: exact fp32 rescore of candidates from emb/W1/b1/W2/b2.
// ---------------------------------------------------------------------------
__global__ __launch_bounds__(256) void rescore(const float* __restrict__ emb,
                                               const float* __restrict__ W1,
                                               const float* __restrict__ b1,
                                               const float* __restrict__ W2,
                                               const float* __restrict__ b2,
                                               const int* __restrict__ eidx,
                                               const unsigned long long* __restrict__ cand,
                                               const unsigned* __restrict__ misc,
                                               unsigned long long* __restrict__ rescored,
                                               int E) {
    __shared__ float es[256], ed[256];
    __shared__ float red[256];
    const int C = (int)min(misc[3], (unsigned)CAND_CAP);
    const int is64 = (int)misc[0];
    const int t = threadIdx.x;
    for (int c = blockIdx.x; c < C; c += gridDim.x) {
        unsigned long long entry = cand[c];
        unsigned e = 0xFFFFFFFFu - (unsigned)(entry & 0xFFFFFFFFu);
        int src, dst;
        if (is64) {
            src = eidx[2 * (size_t)e];
            dst = eidx[2 * ((size_t)e + E)];
        } else {
            src = eidx[e];
            dst = eidx[e + E];
        }
        es[t] = emb[(size_t)src * 256 + t];
        ed[t] = emb[(size_t)dst * 256 + t];
        __syncthreads();
        float h = b1[t];
#pragma unroll 8
        for (int k = 0; k < 256; ++k) h += es[k] * W1[k * 256 + t];
#pragma unroll 8
        for (int k = 0; k < 256; ++k) h += ed[k] * W1[(256 + k) * 256 + t];
        red[t] = fmaxf(h, 0.f) * W2[t];
        __syncthreads();
        for (int s = 128; s; s >>= 1) {
            if (t < s) red[t] += red[t + s];
            __syncthreads();
        }
        if (t == 0) {
            float z = red[0] + b2[0];
            float sc = 1.0f / (1.0f + expf(-z));
            rescored[c] = ((unsigned long long)__float_as_uint(sc) << 32) |
                          (unsigned)(0xFFFFFFFFu - e);
        }
        __syncthreads();
    }
}

// ---------------------------------------------------------------------------
// K8: top-K via single-block LDS bitonic sort (descending), parallel decode.
// key = bits<<32 | ~e  (higher score first, then lower edge index — jax order).
// Fallback to serial removal loop only if C > SORT_CAP (never on this input).
// ---------------------------------------------------------------------------
__global__ __launch_bounds__(256) void final_topk(unsigned long long* __restrict__ rescored,
                                                  const unsigned* __restrict__ misc,
                                                  const int* __restrict__ eidx,
                                                  float* __restrict__ out, int E) {
    __shared__ unsigned long long a[SORT_CAP];
    const int t = threadIdx.x;
    const int C = (int)min(misc[3], (unsigned)CAND_CAP);
    const int is64 = (int)misc[0];

    if (C <= SORT_CAP) {
        int n = 256;
        while (n < C) n <<= 1;
        for (int i = t; i < n; i += 256) a[i] = (i < C) ? rescored[i] : 0ull;
        __syncthreads();
        for (int k = 2; k <= n; k <<= 1) {
            for (int j = k >> 1; j > 0; j >>= 1) {
                for (int i = t; i < n; i += 256) {
                    int ixj = i ^ j;
                    if (ixj > i) {
                        unsigned long long x = a[i], y = a[ixj];
                        bool sw = ((i & k) == 0) ? (x < y) : (x > y);
                        if (sw) { a[i] = y; a[ixj] = x; }
                    }
                }
                __syncthreads();
            }
        }
        if (t < TOPK) {
            unsigned long long m = a[t];
            if (m != 0ull) {
                unsigned bits = (unsigned)(m >> 32);
                unsigned e = 0xFFFFFFFFu - (unsigned)(m & 0xFFFFFFFFu);
                int src, dst;
                if (is64) {
                    src = eidx[2 * (size_t)e];
                    dst = eidx[2 * ((size_t)e + E)];
                } else {
                    src = eidx[e];
                    dst = eidx[e + E];
                }
                out[t] = (float)src;
                out[TOPK + t] = (float)dst;
                out[2 * TOPK + t] = __uint_as_float(bits);
            } else {
                out[t] = -1.f;
                out[TOPK + t] = -1.f;
                out[2 * TOPK + t] = -1.f;
            }
        }
        return;
    }

    // fallback: serial removal tournament over global memory (pathological only)
    __shared__ unsigned long long red[256];
    for (int r = 0; r < TOPK; ++r) {
        unsigned long long best = 0ull;
        for (int i = t; i < C; i += 256) {
            unsigned long long v = rescored[i];
            if (v > best) best = v;
        }
        red[t] = best;
        __syncthreads();
        for (int s = 128; s; s >>= 1) {
            if (t < s) {
                if (red[t + s] > red[t]) red[t] = red[t + s];
            }
            __syncthreads();
        }
        unsigned long long m = red[0];
        __syncthreads();
        for (int i = t; i < C; i += 256)
            if (rescored[i] == m) rescored[i] = 0ull;
        if (t == 0) {
            if (m != 0ull) {
                unsigned bits = (unsigned)(m >> 32);
                unsigned e = 0xFFFFFFFFu - (unsigned)(m & 0xFFFFFFFFu);
                int src, dst;
                if (is64) {
                    src = eidx[2 * (size_t)e];
                    dst = eidx[2 * ((size_t)e + E)];
                } else {
                    src = eidx[e];
                    dst = eidx[e + E];
                }
                out[r] = (float)src;
                out[TOPK + r] = (float)dst;
                out[2 * TOPK + r] = __uint_as_float(bits);
            } else {
                out[r] = -1.f;
                out[TOPK + r] = -1.f;
                out[2 * TOPK + r] = -1.f;
            }
        }
        __syncthreads();
    }
}

// ---------------------------------------------------------------------------
extern "C" void kernel_launch(void* const* d_in, const int* in_sizes, int n_in,
                              void* d_out, int out_size, void* d_ws, size_t ws_size,
                              hipStream_t stream) {
    const float* emb = (const float*)d_in[0];
    const float* W1  = (const float*)d_in[1];
    const float* b1  = (const float*)d_in[2];
    const float* W2  = (const float*)d_in[3];
    const float* b2  = (const float*)d_in[4];
    const int*   eidx = (const int*)d_in[5];

    const int M = in_sizes[0] / 256;           // 50000
    const int E = in_sizes[5] / 2;             // 800000
    const int Mpad = ((M + 127) / 128) * 128;  // 50048

    char* p = (char*)d_ws;
    auto alloc = [&](size_t bytes) {
        char* r = p;
        p += (bytes + 255) & ~(size_t)255;
        return r;
    };
    unsigned* A8f4 = (unsigned*)alloc((size_t)Mpad * 256 * 2);     // bf16 A-frags
    unsigned* Wcf4 = (unsigned*)alloc(256 * 512 * 2);              // bf16 B-frags
    unsigned char* C8 = (unsigned char*)alloc((size_t)Mpad * 512); // fp8 C
    float* svals = (float*)alloc((size_t)E * 4);
    int* vsrc = (int*)alloc((size_t)E * 4);
    int* vdst = (int*)alloc((size_t)E * 4);
    int* vid  = (int*)alloc((size_t)E * 4);
    unsigned* hist = (unsigned*)alloc(HIST_BINS * 4);
    unsigned long long* cand = (unsigned long long*)alloc(CAND_CAP * 8);
    unsigned long long* resc = (unsigned long long*)alloc(CAND_CAP * 8);
    unsigned* bcount = (unsigned*)alloc(NFBLK * 4);
    unsigned* boffset = (unsigned*)alloc(NFBLK * 4);
    unsigned* misc = (unsigned*)alloc(256);

    float* out = (float*)d_out;

    prep_kernel<<<64, 256, 0, stream>>>(W1, Wcf4, hist, misc, eidx);

    cvt_emb<<<Mpad / 16, 256, 0, stream>>>(emb, A8f4, M);

    dim3 ggrid(Mpad / 128, 4);
    gemm_frag<<<ggrid, 256, 0, stream>>>((const bf16x8*)A8f4, (const bf16x8*)Wcf4, b1, C8);

    count_valid<<<NFBLK, 256, 0, stream>>>(eidx, misc, bcount, E);
    scan_blocks<<<1, 256, 0, stream>>>(bcount, boffset, misc);
    write_valid<<<NFBLK, 256, 0, stream>>>(eidx, misc, boffset, vsrc, vdst, vid, E);

    edge_score_fp8<<<2048, 256, 0, stream>>>(C8, vsrc, vdst, W2, b2, svals, misc);

    hist_kernel<<<128, 256, 0, stream>>>(svals, misc, hist);

    scan_hist<<<1, 256, 0, stream>>>(hist, misc);

    compact<<<1024, 256, 0, stream>>>(svals, vid, misc, cand);

    rescore<<<1024, 256, 0, stream>>>(emb, W1, b1, W2, b2, eidx, cand, misc, resc, E);

    final_topk<<<1, 256, 0, stream>>>(resc, misc, eidx, out, E);
}

// Round 9
// 166.088 us; speedup vs baseline: 11.9197x; 1.0069x over previous
//
#include <hip/hip_runtime.h>
#include <hip/hip_bf16.h>
#include <cstdint>

#define TOPK 50
#define CANDS 400          // rank margin for approx threshold
#define HIST_BINS 16384
#define CAND_CAP 16384
#define NFBLK 512          // filter blocks
#define SORT_CAP 8192      // LDS bitonic capacity

typedef __attribute__((ext_vector_type(8))) short bf16x8;
typedef __attribute__((ext_vector_type(4))) float f32x4;

__device__ __forceinline__ unsigned short f2bf(float f) {
    unsigned u = __float_as_uint(f);
    u += 0x7FFFu + ((u >> 16) & 1u);   // RNE
    return (unsigned short)(u >> 16);
}

// ---------------------------------------------------------------------------
// K0: prep — build Wc B-fragments (bf16, MFMA 16x16x32 layout), zero hist,
// detect int64 layout, zero counters.
// ---------------------------------------------------------------------------
__global__ __launch_bounds__(256) void prep_kernel(const float* __restrict__ W1,
                                                   unsigned* __restrict__ Wcf4,
                                                   unsigned* __restrict__ hist,
                                                   unsigned* __restrict__ misc,
                                                   const int* __restrict__ eidx) {
    int g = blockIdx.x * blockDim.x + threadIdx.x;   // 0..16383
    {
        int l = g & 63;
        int kt = (g >> 6) & 7;
        int nt = g >> 9;                 // 0..31
        int col = nt * 16 + (l & 15);
        int kb = kt * 32 + (l >> 4) * 8;
        unsigned short h[8];
#pragma unroll
        for (int j = 0; j < 8; ++j) {
            int k = kb + j;
            float f = (col < 256) ? W1[k * 256 + col] : W1[(256 + k) * 256 + (col - 256)];
            h[j] = f2bf(f);
        }
        unsigned* dst = Wcf4 + (size_t)g * 4;
        dst[0] = (unsigned)h[0] | ((unsigned)h[1] << 16);
        dst[1] = (unsigned)h[2] | ((unsigned)h[3] << 16);
        dst[2] = (unsigned)h[4] | ((unsigned)h[5] << 16);
        dst[3] = (unsigned)h[6] | ((unsigned)h[7] << 16);
    }
    if (g < HIST_BINS) hist[g] = 0;
    if (g == 0) {
        int allz = 1;
        for (int q = 0; q < 64; ++q)
            if (eidx[2 * q + 1] != 0) { allz = 0; break; }
        misc[0] = (unsigned)allz;  // 1 => int64 layout
        misc[2] = 0;               // threshold bits
        misc[3] = 0;               // candidate counter
        misc[4] = 0;               // valid-edge counter
    }
}

// ---------------------------------------------------------------------------
// K1: fused cvt+GEMM. Block = 64 rows x full N=512. emb fp32 staged+converted
// to MFMA A-fragments in LDS (XOR-swizzled); A read from HBM exactly once.
// 4 waves, wave w owns m-tile w (16 rows). N processed in 4 quadrants of 128.
// C stored fp8 e4m3 (+b1 on cols<256).
// ---------------------------------------------------------------------------
__global__ __launch_bounds__(256) void gemm_fused(const float* __restrict__ emb,
                                                  const bf16x8* __restrict__ Bv,
                                                  const float* __restrict__ b1,
                                                  unsigned char* __restrict__ C8, int M) {
    // 32 frags (4 mt x 8 kt) x 64 lanes x 16B = 32 KB
    __shared__ uint4 afrag[2048];
    const int t = threadIdx.x;
    const int w = t >> 6;
    const int l = t & 63;

    // ---- stage: coalesced row-major read, convert, swizzled LDS frag write
    uint2* w2 = (uint2*)afrag;
#pragma unroll
    for (int iter = 0; iter < 16; ++iter) {
        int r = iter * 4 + w;               // 0..63
        int c0 = l * 4;                     // 0..252
        int gr = blockIdx.x * 64 + r;
        float4 v = make_float4(0.f, 0.f, 0.f, 0.f);
        if (gr < M) v = *(const float4*)&emb[(size_t)gr * 256 + c0];
        unsigned u0 = (unsigned)f2bf(v.x) | ((unsigned)f2bf(v.y) << 16);
        unsigned u1 = (unsigned)f2bf(v.z) | ((unsigned)f2bf(v.w) << 16);
        int mt = r >> 4;
        int kt = c0 >> 5;
        int lane = (r & 15) + ((c0 & 31) >> 3) * 16;
        int f = mt * 8 + kt;
        int slot = f * 64 + (lane ^ (f & 7));          // XOR swizzle
        w2[slot * 2 + ((c0 & 7) >> 2)] = make_uint2(u0, u1);
    }
    __syncthreads();

    // ---- load this wave's A-frags (frag f = w*8+kt, f&7 = kt)
    bf16x8 af[8];
#pragma unroll
    for (int kt = 0; kt < 8; ++kt) {
        int f = w * 8 + kt;
        af[kt] = *(const bf16x8*)&afrag[f * 64 + (l ^ kt)];
    }

    const int row0 = blockIdx.x * 64 + w * 16 + (l >> 4) * 4;
#pragma unroll
    for (int nq = 0; nq < 4; ++nq) {
        f32x4 acc[8];
#pragma unroll
        for (int nt = 0; nt < 8; ++nt) acc[nt] = (f32x4){0.f, 0.f, 0.f, 0.f};
#pragma unroll
        for (int kt = 0; kt < 8; ++kt) {
            bf16x8 bf_[8];
#pragma unroll
            for (int nt = 0; nt < 8; ++nt)
                bf_[nt] = Bv[(size_t)((nq * 8 + nt) * 8 + kt) * 64 + l];
#pragma unroll
            for (int nt = 0; nt < 8; ++nt)
                acc[nt] = __builtin_amdgcn_mfma_f32_16x16x32_bf16(af[kt], bf_[nt], acc[nt], 0, 0, 0);
        }
        // epilogue for this quadrant
#pragma unroll
        for (int nt = 0; nt < 8; ++nt) {
            int col = nq * 128 + nt * 16 + (l & 15);
            float bias = (col < 256) ? b1[col] : 0.f;
#pragma unroll
            for (int r = 0; r < 4; ++r) {
                float v = acc[nt][r] + bias;
                int pk = __builtin_amdgcn_cvt_pk_fp8_f32(v, v, 0, false);
                C8[(size_t)(row0 + r) * 512 + col] = (unsigned char)(pk & 0xFF);
            }
        }
    }
}

// ---------------------------------------------------------------------------
// K3a: count valid edges per block chunk (no atomics).
// ---------------------------------------------------------------------------
__global__ __launch_bounds__(256) void count_valid(const int* __restrict__ eidx,
                                                   const unsigned* __restrict__ misc,
                                                   unsigned* __restrict__ bcount, int E) {
    const int is64 = (int)misc[0];
    const int chunk = (E + gridDim.x - 1) / gridDim.x;
    const int lo = blockIdx.x * chunk;
    const int hi = min(E, lo + chunk);
    unsigned cnt = 0;
    for (int e = lo + threadIdx.x; e < hi; e += blockDim.x) {
        int s, d;
        if (is64) {
            s = ((const int2*)eidx)[e].x;
            d = ((const int2*)eidx)[(size_t)e + E].x;
        } else {
            s = eidx[e];
            d = eidx[e + E];
        }
        cnt += (s < d);
    }
#pragma unroll
    for (int off = 32; off; off >>= 1) cnt += __shfl_xor(cnt, off, 64);
    __shared__ unsigned wsum[4];
    if ((threadIdx.x & 63) == 0) wsum[threadIdx.x >> 6] = cnt;
    __syncthreads();
    if (threadIdx.x == 0)
        bcount[blockIdx.x] = wsum[0] + wsum[1] + wsum[2] + wsum[3];
}

// ---------------------------------------------------------------------------
// K3b: exclusive scan of NFBLK block counts -> boffset; total -> misc[4].
// ---------------------------------------------------------------------------
__global__ __launch_bounds__(256) void scan_blocks(const unsigned* __restrict__ bcount,
                                                   unsigned* __restrict__ boffset,
                                                   unsigned* __restrict__ misc) {
    __shared__ unsigned sc[256];
    const int t = threadIdx.x;
    unsigned a = bcount[2 * t], b = bcount[2 * t + 1];
    sc[t] = a + b;
    __syncthreads();
    for (int off = 1; off < 256; off <<= 1) {
        unsigned v = (t >= off) ? sc[t - off] : 0u;
        __syncthreads();
        sc[t] += v;
        __syncthreads();
    }
    unsigned excl = sc[t] - (a + b);
    boffset[2 * t] = excl;
    boffset[2 * t + 1] = excl + a;
    if (t == 255) misc[4] = sc[255];
}

// ---------------------------------------------------------------------------
// K3c: write compacted valid edges at boffset[b] + intra-block prefix.
// ---------------------------------------------------------------------------
__global__ __launch_bounds__(256) void write_valid(const int* __restrict__ eidx,
                                                   const unsigned* __restrict__ misc,
                                                   const unsigned* __restrict__ boffset,
                                                   int* __restrict__ vsrc,
                                                   int* __restrict__ vdst,
                                                   int* __restrict__ vid, int E) {
    const int is64 = (int)misc[0];
    const int chunk = (E + gridDim.x - 1) / gridDim.x;
    const int lo = blockIdx.x * chunk;
    const int hi = min(E, lo + chunk);
    const int lane = threadIdx.x & 63;
    const int w = threadIdx.x >> 6;
    __shared__ unsigned wcnt[4];
    unsigned running = boffset[blockIdx.x];
    for (int base = lo; base < hi; base += blockDim.x) {
        int e = base + threadIdx.x;
        bool valid = false;
        int s = 0, d = 0;
        if (e < hi) {
            if (is64) {
                s = ((const int2*)eidx)[e].x;
                d = ((const int2*)eidx)[(size_t)e + E].x;
            } else {
                s = eidx[e];
                d = eidx[e + E];
            }
            valid = s < d;
        }
        unsigned long long m = __ballot(valid);
        unsigned pfx = __popcll(m & ((1ull << lane) - 1ull));
        if (lane == 0) wcnt[w] = __popcll(m);
        __syncthreads();
        unsigned wbase = running;
        for (int i = 0; i < w; ++i) wbase += wcnt[i];
        if (valid) {
            unsigned p = wbase + pfx;
            vsrc[p] = s;
            vdst[p] = d;
            vid[p] = e;
        }
        unsigned tot = wcnt[0] + wcnt[1] + wcnt[2] + wcnt[3];
        __syncthreads();
        running += tot;
    }
}

// ---------------------------------------------------------------------------
// K4: fp8 edge scoring. 16 lanes/edge, 4 edges/wave. NO atomics.
// ---------------------------------------------------------------------------
__device__ __forceinline__ float dotq(unsigned a, unsigned b, float4 w) {
    float s;
    s  = fmaxf(__builtin_amdgcn_cvt_f32_fp8(a, 0) + __builtin_amdgcn_cvt_f32_fp8(b, 0), 0.f) * w.x;
    s += fmaxf(__builtin_amdgcn_cvt_f32_fp8(a, 1) + __builtin_amdgcn_cvt_f32_fp8(b, 1), 0.f) * w.y;
    s += fmaxf(__builtin_amdgcn_cvt_f32_fp8(a, 2) + __builtin_amdgcn_cvt_f32_fp8(b, 2), 0.f) * w.z;
    s += fmaxf(__builtin_amdgcn_cvt_f32_fp8(a, 3) + __builtin_amdgcn_cvt_f32_fp8(b, 3), 0.f) * w.w;
    return s;
}

__global__ __launch_bounds__(256) void edge_score_fp8(const unsigned char* __restrict__ C8,
                                                      const int* __restrict__ vsrc,
                                                      const int* __restrict__ vdst,
                                                      const float* __restrict__ W2,
                                                      const float* __restrict__ b2,
                                                      float* __restrict__ svals,
                                                      const unsigned* __restrict__ misc) {
    const int V = (int)misc[4];
    const int lane = threadIdx.x & 63;
    const int q = lane & 15;
    const int g = lane >> 4;
    const int wid = blockIdx.x * (blockDim.x >> 6) + (threadIdx.x >> 6);
    const int nw = gridDim.x * (blockDim.x >> 6);

    const float4 w0 = *(const float4*)&W2[q * 16 + 0];
    const float4 w1 = *(const float4*)&W2[q * 16 + 4];
    const float4 w2 = *(const float4*)&W2[q * 16 + 8];
    const float4 w3 = *(const float4*)&W2[q * 16 + 12];
    const float bb2 = b2[0];

    for (int base = wid * 4; base < V; base += nw * 4) {
        const int slot = base + g;
        const bool ok = slot < V;
        const int src = ok ? vsrc[slot] : 0;
        const int dst = ok ? vdst[slot] : 0;
        const uint4 ua = *(const uint4*)(C8 + (size_t)src * 512 + q * 16);
        const uint4 ub = *(const uint4*)(C8 + (size_t)dst * 512 + 256 + q * 16);
        float p = dotq(ua.x, ub.x, w0);
        p += dotq(ua.y, ub.y, w1);
        p += dotq(ua.z, ub.z, w2);
        p += dotq(ua.w, ub.w, w3);
        p += __shfl_xor(p, 1, 64);
        p += __shfl_xor(p, 2, 64);
        p += __shfl_xor(p, 4, 64);
        p += __shfl_xor(p, 8, 64);
        if (q == 0 && ok) {
            float z = p + bb2;
            float sc = 1.0f / (1.0f + expf(-z));
            svals[slot] = sc;
        }
    }
}

// ---------------------------------------------------------------------------
// K4b: histogram — per-block private LDS hist, then merge nonzero bins.
// ---------------------------------------------------------------------------
__global__ __launch_bounds__(256) void hist_kernel(const float* __restrict__ svals,
                                                   const unsigned* __restrict__ misc,
                                                   unsigned* __restrict__ hist) {
    __shared__ unsigned lh[HIST_BINS];
    const int V = (int)misc[4];
    const int t = threadIdx.x;
    for (int i = t; i < HIST_BINS; i += 256) lh[i] = 0;
    __syncthreads();
    int i = blockIdx.x * blockDim.x + t;
    int stride = gridDim.x * blockDim.x;
    for (int v = i; v < V; v += stride)
        atomicAdd(&lh[__float_as_uint(svals[v]) >> 16], 1u);
    __syncthreads();
    for (int b = t; b < HIST_BINS; b += 256) {
        unsigned c = lh[b];
        if (c) atomicAdd(&hist[b], c);
    }
}

// ---------------------------------------------------------------------------
// K5: scan histogram from top — threshold bin containing approx rank CANDS
// ---------------------------------------------------------------------------
__global__ void scan_hist(const unsigned* __restrict__ hist, unsigned* __restrict__ misc) {
    __shared__ unsigned chunk[256];
    int t = threadIdx.x;
    unsigned s = 0;
    for (int i = 0; i < 64; ++i) s += hist[t * 64 + i];
    chunk[t] = s;
    __syncthreads();
    if (t == 0) {
        unsigned cum = 0;
        int c;
        unsigned thr = 0;
        for (c = 255; c >= 0; --c) {
            if (cum + chunk[c] >= CANDS) break;
            cum += chunk[c];
        }
        if (c >= 0) {
            for (int b = c * 64 + 63; b >= c * 64; --b) {
                cum += hist[b];
                if (cum >= CANDS) { thr = ((unsigned)b) << 16; break; }
            }
        }
        misc[2] = thr;
    }
}

// ---------------------------------------------------------------------------
// K6: compact candidates (approx score bits >= threshold)
// ---------------------------------------------------------------------------
__global__ void compact(const float* __restrict__ svals, const int* __restrict__ vid,
                        unsigned* __restrict__ misc,
                        unsigned long long* __restrict__ cand) {
    const int V = (int)misc[4];
    const unsigned thr = misc[2];
    int i = blockIdx.x * blockDim.x + threadIdx.x;
    int stride = gridDim.x * blockDim.x;
    for (int v = i; v < V; v += stride) {
        unsigned bits = __float_as_uint(svals[v]);
        if (bits >= thr) {
            unsigned pos = atomicAdd(&misc[3], 1u);
            if (pos < CAND_CAP)
                cand[pos] = ((unsigned long long)bits << 32) |
                            (unsigned)(0xFFFFFFFFu - (unsigned)vid[v]);
        }
    }
}

// ---------------------------------------------------------------------------
// K7: exact fp32 rescore of candidates from emb/W1/b1/W2/b2.
// ---------------------------------------------------------------------------
__global__ __launch_bounds__(256) void rescore(const float* __restrict__ emb,
                                               const float* __restrict__ W1,
                                               const float* __restrict__ b1,
                                               const float* __restrict__ W2,
                                               const float* __restrict__ b2,
                                               const int* __restrict__ eidx,
                                               const unsigned long long* __restrict__ cand,
                                               const unsigned* __restrict__ misc,
                                               unsigned long long* __restrict__ rescored,
                                               int E) {
    __shared__ float es[256], ed[256];
    __shared__ float red[256];
    const int C = (int)min(misc[3], (unsigned)CAND_CAP);
    const int is64 = (int)misc[0];
    const int t = threadIdx.x;
    for (int c = blockIdx.x; c < C; c += gridDim.x) {
        unsigned long long entry = cand[c];
        unsigned e = 0xFFFFFFFFu - (unsigned)(entry & 0xFFFFFFFFu);
        int src, dst;
        if (is64) {
            src = eidx[2 * (size_t)e];
            dst = eidx[2 * ((size_t)e + E)];
        } else {
            src = eidx[e];
            dst = eidx[e + E];
        }
        es[t] = emb[(size_t)src * 256 + t];
        ed[t] = emb[(size_t)dst * 256 + t];
        __syncthreads();
        float h = b1[t];
#pragma unroll 8
        for (int k = 0; k < 256; ++k) h += es[k] * W1[k * 256 + t];
#pragma unroll 8
        for (int k = 0; k < 256; ++k) h += ed[k] * W1[(256 + k) * 256 + t];
        red[t] = fmaxf(h, 0.f) * W2[t];
        __syncthreads();
        for (int s = 128; s; s >>= 1) {
            if (t < s) red[t] += red[t + s];
            __syncthreads();
        }
        if (t == 0) {
            float z = red[0] + b2[0];
            float sc = 1.0f / (1.0f + expf(-z));
            rescored[c] = ((unsigned long long)__float_as_uint(sc) << 32) |
                          (unsigned)(0xFFFFFFFFu - e);
        }
        __syncthreads();
    }
}

// ---------------------------------------------------------------------------
// K8: top-K via single-block LDS bitonic sort (descending), parallel decode.
// ---------------------------------------------------------------------------
__global__ __launch_bounds__(256) void final_topk(unsigned long long* __restrict__ rescored,
                                                  const unsigned* __restrict__ misc,
                                                  const int* __restrict__ eidx,
                                                  float* __restrict__ out, int E) {
    __shared__ unsigned long long a[SORT_CAP];
    const int t = threadIdx.x;
    const int C = (int)min(misc[3], (unsigned)CAND_CAP);
    const int is64 = (int)misc[0];

    if (C <= SORT_CAP) {
        int n = 256;
        while (n < C) n <<= 1;
        for (int i = t; i < n; i += 256) a[i] = (i < C) ? rescored[i] : 0ull;
        __syncthreads();
        for (int k = 2; k <= n; k <<= 1) {
            for (int j = k >> 1; j > 0; j >>= 1) {
                for (int i = t; i < n; i += 256) {
                    int ixj = i ^ j;
                    if (ixj > i) {
                        unsigned long long x = a[i], y = a[ixj];
                        bool sw = ((i & k) == 0) ? (x < y) : (x > y);
                        if (sw) { a[i] = y; a[ixj] = x; }
                    }
                }
                __syncthreads();
            }
        }
        if (t < TOPK) {
            unsigned long long m = a[t];
            if (m != 0ull) {
                unsigned bits = (unsigned)(m >> 32);
                unsigned e = 0xFFFFFFFFu - (unsigned)(m & 0xFFFFFFFFu);
                int src, dst;
                if (is64) {
                    src = eidx[2 * (size_t)e];
                    dst = eidx[2 * ((size_t)e + E)];
                } else {
                    src = eidx[e];
                    dst = eidx[e + E];
                }
                out[t] = (float)src;
                out[TOPK + t] = (float)dst;
                out[2 * TOPK + t] = __uint_as_float(bits);
            } else {
                out[t] = -1.f;
                out[TOPK + t] = -1.f;
                out[2 * TOPK + t] = -1.f;
            }
        }
        return;
    }

    // fallback: serial removal tournament (pathological only)
    __shared__ unsigned long long red[256];
    for (int r = 0; r < TOPK; ++r) {
        unsigned long long best = 0ull;
        for (int i = t; i < C; i += 256) {
            unsigned long long v = rescored[i];
            if (v > best) best = v;
        }
        red[t] = best;
        __syncthreads();
        for (int s = 128; s; s >>= 1) {
            if (t < s) {
                if (red[t + s] > red[t]) red[t] = red[t + s];
            }
            __syncthreads();
        }
        unsigned long long m = red[0];
        __syncthreads();
        for (int i = t; i < C; i += 256)
            if (rescored[i] == m) rescored[i] = 0ull;
        if (t == 0) {
            if (m != 0ull) {
                unsigned bits = (unsigned)(m >> 32);
                unsigned e = 0xFFFFFFFFu - (unsigned)(m & 0xFFFFFFFFu);
                int src, dst;
                if (is64) {
                    src = eidx[2 * (size_t)e];
                    dst = eidx[2 * ((size_t)e + E)];
                } else {
                    src = eidx[e];
                    dst = eidx[e + E];
                }
                out[r] = (float)src;
                out[TOPK + r] = (float)dst;
                out[2 * TOPK + r] = __uint_as_float(bits);
            } else {
                out[r] = -1.f;
                out[TOPK + r] = -1.f;
                out[2 * TOPK + r] = -1.f;
            }
        }
        __syncthreads();
    }
}

// ---------------------------------------------------------------------------
extern "C" void kernel_launch(void* const* d_in, const int* in_sizes, int n_in,
                              void* d_out, int out_size, void* d_ws, size_t ws_size,
                              hipStream_t stream) {
    const float* emb = (const float*)d_in[0];
    const float* W1  = (const float*)d_in[1];
    const float* b1  = (const float*)d_in[2];
    const float* W2  = (const float*)d_in[3];
    const float* b2  = (const float*)d_in[4];
    const int*   eidx = (const int*)d_in[5];

    const int M = in_sizes[0] / 256;           // 50000
    const int E = in_sizes[5] / 2;             // 800000
    const int Mpad = ((M + 63) / 64) * 64;     // 50048

    char* p = (char*)d_ws;
    auto alloc = [&](size_t bytes) {
        char* r = p;
        p += (bytes + 255) & ~(size_t)255;
        return r;
    };
    unsigned* Wcf4 = (unsigned*)alloc(256 * 512 * 2);              // bf16 B-frags
    unsigned char* C8 = (unsigned char*)alloc((size_t)Mpad * 512); // fp8 C
    float* svals = (float*)alloc((size_t)E * 4);
    int* vsrc = (int*)alloc((size_t)E * 4);
    int* vdst = (int*)alloc((size_t)E * 4);
    int* vid  = (int*)alloc((size_t)E * 4);
    unsigned* hist = (unsigned*)alloc(HIST_BINS * 4);
    unsigned long long* cand = (unsigned long long*)alloc(CAND_CAP * 8);
    unsigned long long* resc = (unsigned long long*)alloc(CAND_CAP * 8);
    unsigned* bcount = (unsigned*)alloc(NFBLK * 4);
    unsigned* boffset = (unsigned*)alloc(NFBLK * 4);
    unsigned* misc = (unsigned*)alloc(256);

    float* out = (float*)d_out;

    prep_kernel<<<64, 256, 0, stream>>>(W1, Wcf4, hist, misc, eidx);

    gemm_fused<<<Mpad / 64, 256, 0, stream>>>(emb, (const bf16x8*)Wcf4, b1, C8, M);

    count_valid<<<NFBLK, 256, 0, stream>>>(eidx, misc, bcount, E);
    scan_blocks<<<1, 256, 0, stream>>>(bcount, boffset, misc);
    write_valid<<<NFBLK, 256, 0, stream>>>(eidx, misc, boffset, vsrc, vdst, vid, E);

    edge_score_fp8<<<2048, 256, 0, stream>>>(C8, vsrc, vdst, W2, b2, svals, misc);

    hist_kernel<<<128, 256, 0, stream>>>(svals, misc, hist);

    scan_hist<<<1, 256, 0, stream>>>(hist, misc);

    compact<<<1024, 256, 0, stream>>>(svals, vid, misc, cand);

    rescore<<<1024, 256, 0, stream>>>(emb, W1, b1, W2, b2, eidx, cand, misc, resc, E);

    final_topk<<<1, 256, 0, stream>>>(resc, misc, eidx, out, E);
}

// Round 10
// 163.574 us; speedup vs baseline: 12.1029x; 1.0154x over previous
//
#include <hip/hip_runtime.h>
#include <hip/hip_bf16.h>
#include <cstdint>

#define TOPK 50
#define CANDS 400          // rank margin for approx threshold
#define HIST_BINS 16384
#define CAND_CAP 16384
#define NFBLK 512          // filter blocks
#define SORT_CAP 8192      // LDS bitonic capacity

typedef __attribute__((ext_vector_type(8))) short bf16x8;
typedef __attribute__((ext_vector_type(4))) float f32x4;

__device__ __forceinline__ unsigned short f2bf(float f) {
    unsigned u = __float_as_uint(f);
    u += 0x7FFFu + ((u >> 16) & 1u);   // RNE
    return (unsigned short)(u >> 16);
}

// ---------------------------------------------------------------------------
// K0: prep — build Wc B-fragments (bf16, MFMA 16x16x32 layout), zero hist,
// detect int64 layout, zero counters.
// ---------------------------------------------------------------------------
__global__ __launch_bounds__(256) void prep_kernel(const float* __restrict__ W1,
                                                   unsigned* __restrict__ Wcf4,
                                                   unsigned* __restrict__ hist,
                                                   unsigned* __restrict__ misc,
                                                   const int* __restrict__ eidx) {
    int g = blockIdx.x * blockDim.x + threadIdx.x;   // 0..16383
    {
        int l = g & 63;
        int kt = (g >> 6) & 7;
        int nt = g >> 9;                 // 0..31
        int col = nt * 16 + (l & 15);
        int kb = kt * 32 + (l >> 4) * 8;
        unsigned short h[8];
#pragma unroll
        for (int j = 0; j < 8; ++j) {
            int k = kb + j;
            float f = (col < 256) ? W1[k * 256 + col] : W1[(256 + k) * 256 + (col - 256)];
            h[j] = f2bf(f);
        }
        unsigned* dst = Wcf4 + (size_t)g * 4;
        dst[0] = (unsigned)h[0] | ((unsigned)h[1] << 16);
        dst[1] = (unsigned)h[2] | ((unsigned)h[3] << 16);
        dst[2] = (unsigned)h[4] | ((unsigned)h[5] << 16);
        dst[3] = (unsigned)h[6] | ((unsigned)h[7] << 16);
    }
    if (g < HIST_BINS) hist[g] = 0;
    if (g == 0) {
        int allz = 1;
        for (int q = 0; q < 64; ++q)
            if (eidx[2 * q + 1] != 0) { allz = 0; break; }
        misc[0] = (unsigned)allz;  // 1 => int64 layout
        misc[2] = 0;               // threshold bits
        misc[3] = 0;               // candidate counter
        misc[4] = 0;               // valid-edge counter
    }
}

// ---------------------------------------------------------------------------
// K1: fused cvt+GEMM. Block = 128 rows x full N=512, 1024 threads (16 waves
// = 4m x 4n). Wave owns 32 rows x 128 cols (2 mt x 8 nt): per kt 2 A-frag LDS
// reads + 8 B loads + 16 MFMA (B:MFMA = 1:2). A read from HBM/L3 exactly once
// per block, converted to XOR-swizzled MFMA fragments in 64 KB LDS.
// C stored fp8 e4m3 (+b1 on cols<256).
// ---------------------------------------------------------------------------
__global__ __launch_bounds__(1024) void gemm_fused(const float* __restrict__ emb,
                                                   const bf16x8* __restrict__ Bv,
                                                   const float* __restrict__ b1,
                                                   unsigned char* __restrict__ C8, int M) {
    // 64 frags (8 mt x 8 kt) x 64 lanes x 16B = 64 KB
    __shared__ uint4 afrag[4096];
    const int t = threadIdx.x;
    const int w = t >> 6;          // 0..15
    const int l = t & 63;

    // ---- stage: coalesced row-major read, convert, swizzled LDS frag write
    uint2* w2 = (uint2*)afrag;
#pragma unroll
    for (int iter = 0; iter < 8; ++iter) {
        int flat = iter * 1024 + t;        // 0..8191
        int r = flat >> 6;                 // 0..127
        int c0 = (flat & 63) * 4;          // 0..252
        int gr = blockIdx.x * 128 + r;
        float4 v = make_float4(0.f, 0.f, 0.f, 0.f);
        if (gr < M) v = *(const float4*)&emb[(size_t)gr * 256 + c0];
        unsigned u0 = (unsigned)f2bf(v.x) | ((unsigned)f2bf(v.y) << 16);
        unsigned u1 = (unsigned)f2bf(v.z) | ((unsigned)f2bf(v.w) << 16);
        int mt = r >> 4;                   // 0..7
        int kt = c0 >> 5;                  // 0..7
        int lane = (r & 15) + ((c0 & 31) >> 3) * 16;
        int f = mt * 8 + kt;               // 0..63
        int slot = f * 64 + (lane ^ (f & 7));          // XOR swizzle
        w2[slot * 2 + ((c0 & 7) >> 2)] = make_uint2(u0, u1);
    }
    __syncthreads();

    const int wm = w >> 2;         // 0..3  -> rows wm*32 .. wm*32+31
    const int wn = w & 3;          // 0..3  -> cols wn*128 .. wn*128+127

    f32x4 acc[2][8];
#pragma unroll
    for (int i = 0; i < 2; ++i)
#pragma unroll
        for (int j = 0; j < 8; ++j) acc[i][j] = (f32x4){0.f, 0.f, 0.f, 0.f};

#pragma unroll
    for (int kt = 0; kt < 8; ++kt) {
        bf16x8 af[2];
#pragma unroll
        for (int i = 0; i < 2; ++i) {
            int f = (wm * 2 + i) * 8 + kt;
            af[i] = *(const bf16x8*)&afrag[f * 64 + (l ^ (f & 7))];
        }
#pragma unroll
        for (int j = 0; j < 8; ++j) {
            bf16x8 bf_ = Bv[(size_t)((wn * 8 + j) * 8 + kt) * 64 + l];
            acc[0][j] = __builtin_amdgcn_mfma_f32_16x16x32_bf16(af[0], bf_, acc[0][j], 0, 0, 0);
            acc[1][j] = __builtin_amdgcn_mfma_f32_16x16x32_bf16(af[1], bf_, acc[1][j], 0, 0, 0);
        }
    }

    // epilogue
#pragma unroll
    for (int i = 0; i < 2; ++i) {
        int row0 = blockIdx.x * 128 + (wm * 2 + i) * 16 + (l >> 4) * 4;
#pragma unroll
        for (int j = 0; j < 8; ++j) {
            int col = wn * 128 + j * 16 + (l & 15);
            float bias = (col < 256) ? b1[col] : 0.f;
#pragma unroll
            for (int r = 0; r < 4; ++r) {
                float v = acc[i][j][r] + bias;
                int pk = __builtin_amdgcn_cvt_pk_fp8_f32(v, v, 0, false);
                C8[(size_t)(row0 + r) * 512 + col] = (unsigned char)(pk & 0xFF);
            }
        }
    }
}

// ---------------------------------------------------------------------------
// K3a: count valid edges per block chunk (no atomics).
// ---------------------------------------------------------------------------
__global__ __launch_bounds__(256) void count_valid(const int* __restrict__ eidx,
                                                   const unsigned* __restrict__ misc,
                                                   unsigned* __restrict__ bcount, int E) {
    const int is64 = (int)misc[0];
    const int chunk = (E + gridDim.x - 1) / gridDim.x;
    const int lo = blockIdx.x * chunk;
    const int hi = min(E, lo + chunk);
    unsigned cnt = 0;
    for (int e = lo + threadIdx.x; e < hi; e += blockDim.x) {
        int s, d;
        if (is64) {
            s = ((const int2*)eidx)[e].x;
            d = ((const int2*)eidx)[(size_t)e + E].x;
        } else {
            s = eidx[e];
            d = eidx[e + E];
        }
        cnt += (s < d);
    }
#pragma unroll
    for (int off = 32; off; off >>= 1) cnt += __shfl_xor(cnt, off, 64);
    __shared__ unsigned wsum[4];
    if ((threadIdx.x & 63) == 0) wsum[threadIdx.x >> 6] = cnt;
    __syncthreads();
    if (threadIdx.x == 0)
        bcount[blockIdx.x] = wsum[0] + wsum[1] + wsum[2] + wsum[3];
}

// ---------------------------------------------------------------------------
// K3b: exclusive scan of NFBLK block counts -> boffset; total -> misc[4].
// ---------------------------------------------------------------------------
__global__ __launch_bounds__(256) void scan_blocks(const unsigned* __restrict__ bcount,
                                                   unsigned* __restrict__ boffset,
                                                   unsigned* __restrict__ misc) {
    __shared__ unsigned sc[256];
    const int t = threadIdx.x;
    unsigned a = bcount[2 * t], b = bcount[2 * t + 1];
    sc[t] = a + b;
    __syncthreads();
    for (int off = 1; off < 256; off <<= 1) {
        unsigned v = (t >= off) ? sc[t - off] : 0u;
        __syncthreads();
        sc[t] += v;
        __syncthreads();
    }
    unsigned excl = sc[t] - (a + b);
    boffset[2 * t] = excl;
    boffset[2 * t + 1] = excl + a;
    if (t == 255) misc[4] = sc[255];
}

// ---------------------------------------------------------------------------
// K3c: write compacted valid edges at boffset[b] + intra-block prefix.
// ---------------------------------------------------------------------------
__global__ __launch_bounds__(256) void write_valid(const int* __restrict__ eidx,
                                                   const unsigned* __restrict__ misc,
                                                   const unsigned* __restrict__ boffset,
                                                   int* __restrict__ vsrc,
                                                   int* __restrict__ vdst,
                                                   int* __restrict__ vid, int E) {
    const int is64 = (int)misc[0];
    const int chunk = (E + gridDim.x - 1) / gridDim.x;
    const int lo = blockIdx.x * chunk;
    const int hi = min(E, lo + chunk);
    const int lane = threadIdx.x & 63;
    const int w = threadIdx.x >> 6;
    __shared__ unsigned wcnt[4];
    unsigned running = boffset[blockIdx.x];
    for (int base = lo; base < hi; base += blockDim.x) {
        int e = base + threadIdx.x;
        bool valid = false;
        int s = 0, d = 0;
        if (e < hi) {
            if (is64) {
                s = ((const int2*)eidx)[e].x;
                d = ((const int2*)eidx)[(size_t)e + E].x;
            } else {
                s = eidx[e];
                d = eidx[e + E];
            }
            valid = s < d;
        }
        unsigned long long m = __ballot(valid);
        unsigned pfx = __popcll(m & ((1ull << lane) - 1ull));
        if (lane == 0) wcnt[w] = __popcll(m);
        __syncthreads();
        unsigned wbase = running;
        for (int i = 0; i < w; ++i) wbase += wcnt[i];
        if (valid) {
            unsigned p = wbase + pfx;
            vsrc[p] = s;
            vdst[p] = d;
            vid[p] = e;
        }
        unsigned tot = wcnt[0] + wcnt[1] + wcnt[2] + wcnt[3];
        __syncthreads();
        running += tot;
    }
}

// ---------------------------------------------------------------------------
// K4: fp8 edge scoring. 16 lanes/edge, 4 edges/wave. NO atomics.
// ---------------------------------------------------------------------------
__device__ __forceinline__ float dotq(unsigned a, unsigned b, float4 w) {
    float s;
    s  = fmaxf(__builtin_amdgcn_cvt_f32_fp8(a, 0) + __builtin_amdgcn_cvt_f32_fp8(b, 0), 0.f) * w.x;
    s += fmaxf(__builtin_amdgcn_cvt_f32_fp8(a, 1) + __builtin_amdgcn_cvt_f32_fp8(b, 1), 0.f) * w.y;
    s += fmaxf(__builtin_amdgcn_cvt_f32_fp8(a, 2) + __builtin_amdgcn_cvt_f32_fp8(b, 2), 0.f) * w.z;
    s += fmaxf(__builtin_amdgcn_cvt_f32_fp8(a, 3) + __builtin_amdgcn_cvt_f32_fp8(b, 3), 0.f) * w.w;
    return s;
}

__global__ __launch_bounds__(256) void edge_score_fp8(const unsigned char* __restrict__ C8,
                                                      const int* __restrict__ vsrc,
                                                      const int* __restrict__ vdst,
                                                      const float* __restrict__ W2,
                                                      const float* __restrict__ b2,
                                                      float* __restrict__ svals,
                                                      const unsigned* __restrict__ misc) {
    const int V = (int)misc[4];
    const int lane = threadIdx.x & 63;
    const int q = lane & 15;
    const int g = lane >> 4;
    const int wid = blockIdx.x * (blockDim.x >> 6) + (threadIdx.x >> 6);
    const int nw = gridDim.x * (blockDim.x >> 6);

    const float4 w0 = *(const float4*)&W2[q * 16 + 0];
    const float4 w1 = *(const float4*)&W2[q * 16 + 4];
    const float4 w2 = *(const float4*)&W2[q * 16 + 8];
    const float4 w3 = *(const float4*)&W2[q * 16 + 12];
    const float bb2 = b2[0];

    for (int base = wid * 4; base < V; base += nw * 4) {
        const int slot = base + g;
        const bool ok = slot < V;
        const int src = ok ? vsrc[slot] : 0;
        const int dst = ok ? vdst[slot] : 0;
        const uint4 ua = *(const uint4*)(C8 + (size_t)src * 512 + q * 16);
        const uint4 ub = *(const uint4*)(C8 + (size_t)dst * 512 + 256 + q * 16);
        float p = dotq(ua.x, ub.x, w0);
        p += dotq(ua.y, ub.y, w1);
        p += dotq(ua.z, ub.z, w2);
        p += dotq(ua.w, ub.w, w3);
        p += __shfl_xor(p, 1, 64);
        p += __shfl_xor(p, 2, 64);
        p += __shfl_xor(p, 4, 64);
        p += __shfl_xor(p, 8, 64);
        if (q == 0 && ok) {
            float z = p + bb2;
            float sc = 1.0f / (1.0f + expf(-z));
            svals[slot] = sc;
        }
    }
}

// ---------------------------------------------------------------------------
// K4b: histogram — per-block private LDS hist, then merge nonzero bins.
// ---------------------------------------------------------------------------
__global__ __launch_bounds__(256) void hist_kernel(const float* __restrict__ svals,
                                                   const unsigned* __restrict__ misc,
                                                   unsigned* __restrict__ hist) {
    __shared__ unsigned lh[HIST_BINS];
    const int V = (int)misc[4];
    const int t = threadIdx.x;
    for (int i = t; i < HIST_BINS; i += 256) lh[i] = 0;
    __syncthreads();
    int i = blockIdx.x * blockDim.x + t;
    int stride = gridDim.x * blockDim.x;
    for (int v = i; v < V; v += stride)
        atomicAdd(&lh[__float_as_uint(svals[v]) >> 16], 1u);
    __syncthreads();
    for (int b = t; b < HIST_BINS; b += 256) {
        unsigned c = lh[b];
        if (c) atomicAdd(&hist[b], c);
    }
}

// ---------------------------------------------------------------------------
// K5: scan histogram from top — threshold bin containing approx rank CANDS
// ---------------------------------------------------------------------------
__global__ void scan_hist(const unsigned* __restrict__ hist, unsigned* __restrict__ misc) {
    __shared__ unsigned chunk[256];
    int t = threadIdx.x;
    unsigned s = 0;
    for (int i = 0; i < 64; ++i) s += hist[t * 64 + i];
    chunk[t] = s;
    __syncthreads();
    if (t == 0) {
        unsigned cum = 0;
        int c;
        unsigned thr = 0;
        for (c = 255; c >= 0; --c) {
            if (cum + chunk[c] >= CANDS) break;
            cum += chunk[c];
        }
        if (c >= 0) {
            for (int b = c * 64 + 63; b >= c * 64; --b) {
                cum += hist[b];
                if (cum >= CANDS) { thr = ((unsigned)b) << 16; break; }
            }
        }
        misc[2] = thr;
    }
}

// ---------------------------------------------------------------------------
// K6: compact candidates (approx score bits >= threshold)
// ---------------------------------------------------------------------------
__global__ void compact(const float* __restrict__ svals, const int* __restrict__ vid,
                        unsigned* __restrict__ misc,
                        unsigned long long* __restrict__ cand) {
    const int V = (int)misc[4];
    const unsigned thr = misc[2];
    int i = blockIdx.x * blockDim.x + threadIdx.x;
    int stride = gridDim.x * blockDim.x;
    for (int v = i; v < V; v += stride) {
        unsigned bits = __float_as_uint(svals[v]);
        if (bits >= thr) {
            unsigned pos = atomicAdd(&misc[3], 1u);
            if (pos < CAND_CAP)
                cand[pos] = ((unsigned long long)bits << 32) |
                            (unsigned)(0xFFFFFFFFu - (unsigned)vid[v]);
        }
    }
}

// ---------------------------------------------------------------------------
// K7: exact fp32 rescore of candidates from emb/W1/b1/W2/b2.
// ---------------------------------------------------------------------------
__global__ __launch_bounds__(256) void rescore(const float* __restrict__ emb,
                                               const float* __restrict__ W1,
                                               const float* __restrict__ b1,
                                               const float* __restrict__ W2,
                                               const float* __restrict__ b2,
                                               const int* __restrict__ eidx,
                                               const unsigned long long* __restrict__ cand,
                                               const unsigned* __restrict__ misc,
                                               unsigned long long* __restrict__ rescored,
                                               int E) {
    __shared__ float es[256], ed[256];
    __shared__ float red[256];
    const int C = (int)min(misc[3], (unsigned)CAND_CAP);
    const int is64 = (int)misc[0];
    const int t = threadIdx.x;
    for (int c = blockIdx.x; c < C; c += gridDim.x) {
        unsigned long long entry = cand[c];
        unsigned e = 0xFFFFFFFFu - (unsigned)(entry & 0xFFFFFFFFu);
        int src, dst;
        if (is64) {
            src = eidx[2 * (size_t)e];
            dst = eidx[2 * ((size_t)e + E)];
        } else {
            src = eidx[e];
            dst = eidx[e + E];
        }
        es[t] = emb[(size_t)src * 256 + t];
        ed[t] = emb[(size_t)dst * 256 + t];
        __syncthreads();
        float h = b1[t];
#pragma unroll 8
        for (int k = 0; k < 256; ++k) h += es[k] * W1[k * 256 + t];
#pragma unroll 8
        for (int k = 0; k < 256; ++k) h += ed[k] * W1[(256 + k) * 256 + t];
        red[t] = fmaxf(h, 0.f) * W2[t];
        __syncthreads();
        for (int s = 128; s; s >>= 1) {
            if (t < s) red[t] += red[t + s];
            __syncthreads();
        }
        if (t == 0) {
            float z = red[0] + b2[0];
            float sc = 1.0f / (1.0f + expf(-z));
            rescored[c] = ((unsigned long long)__float_as_uint(sc) << 32) |
                          (unsigned)(0xFFFFFFFFu - e);
        }
        __syncthreads();
    }
}

// ---------------------------------------------------------------------------
// K8: top-K via single-block LDS bitonic sort (descending), parallel decode.
// ---------------------------------------------------------------------------
__global__ __launch_bounds__(256) void final_topk(unsigned long long* __restrict__ rescored,
                                                  const unsigned* __restrict__ misc,
                                                  const int* __restrict__ eidx,
                                                  float* __restrict__ out, int E) {
    __shared__ unsigned long long a[SORT_CAP];
    const int t = threadIdx.x;
    const int C = (int)min(misc[3], (unsigned)CAND_CAP);
    const int is64 = (int)misc[0];

    if (C <= SORT_CAP) {
        int n = 256;
        while (n < C) n <<= 1;
        for (int i = t; i < n; i += 256) a[i] = (i < C) ? rescored[i] : 0ull;
        __syncthreads();
        for (int k = 2; k <= n; k <<= 1) {
            for (int j = k >> 1; j > 0; j >>= 1) {
                for (int i = t; i < n; i += 256) {
                    int ixj = i ^ j;
                    if (ixj > i) {
                        unsigned long long x = a[i], y = a[ixj];
                        bool sw = ((i & k) == 0) ? (x < y) : (x > y);
                        if (sw) { a[i] = y; a[ixj] = x; }
                    }
                }
                __syncthreads();
            }
        }
        if (t < TOPK) {
            unsigned long long m = a[t];
            if (m != 0ull) {
                unsigned bits = (unsigned)(m >> 32);
                unsigned e = 0xFFFFFFFFu - (unsigned)(m & 0xFFFFFFFFu);
                int src, dst;
                if (is64) {
                    src = eidx[2 * (size_t)e];
                    dst = eidx[2 * ((size_t)e + E)];
                } else {
                    src = eidx[e];
                    dst = eidx[e + E];
                }
                out[t] = (float)src;
                out[TOPK + t] = (float)dst;
                out[2 * TOPK + t] = __uint_as_float(bits);
            } else {
                out[t] = -1.f;
                out[TOPK + t] = -1.f;
                out[2 * TOPK + t] = -1.f;
            }
        }
        return;
    }

    // fallback: serial removal tournament (pathological only)
    __shared__ unsigned long long red[256];
    for (int r = 0; r < TOPK; ++r) {
        unsigned long long best = 0ull;
        for (int i = t; i < C; i += 256) {
            unsigned long long v = rescored[i];
            if (v > best) best = v;
        }
        red[t] = best;
        __syncthreads();
        for (int s = 128; s; s >>= 1) {
            if (t < s) {
                if (red[t + s] > red[t]) red[t] = red[t + s];
            }
            __syncthreads();
        }
        unsigned long long m = red[0];
        __syncthreads();
        for (int i = t; i < C; i += 256)
            if (rescored[i] == m) rescored[i] = 0ull;
        if (t == 0) {
            if (m != 0ull) {
                unsigned bits = (unsigned)(m >> 32);
                unsigned e = 0xFFFFFFFFu - (unsigned)(m & 0xFFFFFFFFu);
                int src, dst;
                if (is64) {
                    src = eidx[2 * (size_t)e];
                    dst = eidx[2 * ((size_t)e + E)];
                } else {
                    src = eidx[e];
                    dst = eidx[e + E];
                }
                out[r] = (float)src;
                out[TOPK + r] = (float)dst;
                out[2 * TOPK + r] = __uint_as_float(bits);
            } else {
                out[r] = -1.f;
                out[TOPK + r] = -1.f;
                out[2 * TOPK + r] = -1.f;
            }
        }
        __syncthreads();
    }
}

// ---------------------------------------------------------------------------
extern "C" void kernel_launch(void* const* d_in, const int* in_sizes, int n_in,
                              void* d_out, int out_size, void* d_ws, size_t ws_size,
                              hipStream_t stream) {
    const float* emb = (const float*)d_in[0];
    const float* W1  = (const float*)d_in[1];
    const float* b1  = (const float*)d_in[2];
    const float* W2  = (const float*)d_in[3];
    const float* b2  = (const float*)d_in[4];
    const int*   eidx = (const int*)d_in[5];

    const int M = in_sizes[0] / 256;           // 50000
    const int E = in_sizes[5] / 2;             // 800000
    const int Mpad = ((M + 127) / 128) * 128;  // 50048

    char* p = (char*)d_ws;
    auto alloc = [&](size_t bytes) {
        char* r = p;
        p += (bytes + 255) & ~(size_t)255;
        return r;
    };
    unsigned* Wcf4 = (unsigned*)alloc(256 * 512 * 2);              // bf16 B-frags
    unsigned char* C8 = (unsigned char*)alloc((size_t)Mpad * 512); // fp8 C
    float* svals = (float*)alloc((size_t)E * 4);
    int* vsrc = (int*)alloc((size_t)E * 4);
    int* vdst = (int*)alloc((size_t)E * 4);
    int* vid  = (int*)alloc((size_t)E * 4);
    unsigned* hist = (unsigned*)alloc(HIST_BINS * 4);
    unsigned long long* cand = (unsigned long long*)alloc(CAND_CAP * 8);
    unsigned long long* resc = (unsigned long long*)alloc(CAND_CAP * 8);
    unsigned* bcount = (unsigned*)alloc(NFBLK * 4);
    unsigned* boffset = (unsigned*)alloc(NFBLK * 4);
    unsigned* misc = (unsigned*)alloc(256);

    float* out = (float*)d_out;

    prep_kernel<<<64, 256, 0, stream>>>(W1, Wcf4, hist, misc, eidx);

    gemm_fused<<<Mpad / 128, 1024, 0, stream>>>(emb, (const bf16x8*)Wcf4, b1, C8, M);

    count_valid<<<NFBLK, 256, 0, stream>>>(eidx, misc, bcount, E);
    scan_blocks<<<1, 256, 0, stream>>>(bcount, boffset, misc);
    write_valid<<<NFBLK, 256, 0, stream>>>(eidx, misc, boffset, vsrc, vdst, vid, E);

    edge_score_fp8<<<2048, 256, 0, stream>>>(C8, vsrc, vdst, W2, b2, svals, misc);

    hist_kernel<<<128, 256, 0, stream>>>(svals, misc, hist);

    scan_hist<<<1, 256, 0, stream>>>(hist, misc);

    compact<<<1024, 256, 0, stream>>>(svals, vid, misc, cand);

    rescore<<<1024, 256, 0, stream>>>(emb, W1, b1, W2, b2, eidx, cand, misc, resc, E);

    final_topk<<<1, 256, 0, stream>>>(resc, misc, eidx, out, E);
}